// Round 6
// baseline (417.359 us; speedup 1.0000x reference)
//
#include <hip/hip_runtime.h>
#include <math.h>

// Problem constants
#define NB 8
#define SEQ 1024
#define DM 1536
#define NHEAD 12
#define DHEAD 128
#define MAXC 256
#define QKVN 4608
#define THRESH 0.85f

typedef unsigned short u16;
typedef __attribute__((ext_vector_type(8))) __bf16 bf16x8;
typedef __attribute__((ext_vector_type(4))) float f32x4;

struct __align__(4) U2 { u16 x, y; };
struct __align__(8) U4 { u16 x, y, z, w; };

__device__ __forceinline__ float bf2f(u16 u) {
  union { unsigned i; float f; } c; c.i = ((unsigned)u) << 16; return c.f;
}
__device__ __forceinline__ u16 f2bf(float f) {
  union { float f; unsigned i; } c; c.f = f;
  unsigned r = c.i + 0x7FFFu + ((c.i >> 16) & 1u);  // RNE
  return (u16)(r >> 16);
}

// ---------------------------------------------------------------- converts
__global__ __launch_bounds__(256) void cvt5_bf16_kernel(
    const float* __restrict__ i0, u16* __restrict__ o0, int n0,
    const float* __restrict__ i1, u16* __restrict__ o1, int n1,
    const float* __restrict__ i2, u16* __restrict__ o2, int n2,
    const float* __restrict__ i3, u16* __restrict__ o3, int n3,
    const float* __restrict__ i4, u16* __restrict__ o4, int n4) {
  const int stride = gridDim.x * blockDim.x;
  const int t0 = blockIdx.x * blockDim.x + threadIdx.x;
  const float* ins[5] = {i0, i1, i2, i3, i4};
  u16* outs[5] = {o0, o1, o2, o3, o4};
  const int ns[5] = {n0, n1, n2, n3, n4};
#pragma unroll
  for (int a = 0; a < 5; ++a) {
    const float* in = ins[a];
    u16* out = outs[a];
    for (int i = t0; i < ns[a]; i += stride) {
      float4 f = ((const float4*)in)[i];
      U4 u; u.x = f2bf(f.x); u.y = f2bf(f.y); u.z = f2bf(f.z); u.w = f2bf(f.w);
      ((U4*)out)[i] = u;
    }
  }
}

// ------------------------------------------------------------- segmentation
__global__ __launch_bounds__(64) void segment_kernel(
    const float* __restrict__ bnd, int* __restrict__ nchunks,
    int* __restrict__ starts, int* __restrict__ lens) {
  const int b = blockIdx.x;
  const int lane = threadIdx.x;
  int running = 0;
  for (int g = 0; g < SEQ / 64; ++g) {
    int s = g * 64 + lane;
    bool isb = bnd[b * SEQ + s] > THRESH;
    unsigned long long mask = __ballot(isb ? 1 : 0);
    int excl = __popcll(mask & ((1ULL << lane) - 1ULL));
    if (isb) {
      int c = running + excl;
      if (c <= MAXC) starts[b * (MAXC + 1) + c] = s;
    }
    running += __popcll(mask);
  }
  if (lane == 0) nchunks[b] = running;
  __syncthreads();
  int ncl = min(running, MAXC);
  for (int c = lane; c < MAXC; c += 64) {
    int v = 0;
    if (c < ncl) {
      int st = starts[b * (MAXC + 1) + c];
      int en = (c + 1 < running) ? starts[b * (MAXC + 1) + c + 1] : SEQ;
      v = en - st;
    }
    lens[b * MAXC + c] = v;
  }
}

// --------------------------------------------------- 256x256 pipelined GEMM
__global__ __launch_bounds__(512, 2) void gemm256_kernel(
    const u16* __restrict__ A, const u16* __restrict__ B,
    const int M, const int N, const int K,
    const float* __restrict__ bias, u16* __restrict__ outB) {
  __shared__ __align__(16) u16 lds[3][2][8192];  // [buf][A/B][1024 slots * 8]
  const int tid = threadIdx.x;
  const int wid = tid >> 6;
  const int lane = tid & 63;
  const int cpx = gridDim.x >> 3;
  const int bid = ((int)blockIdx.x & 7) * cpx + ((int)blockIdx.x >> 3);
  const int NX = N >> 8;
  const int row0 = (bid / NX) << 8;
  const int col0 = (bid % NX) << 8;

  const int wr = wid >> 2;
  const int wc = wid & 3;
  const int rr = lane & 15;
  const int kg = lane >> 4;
  const int cw = rr * 4 + kg;
  const int slot = cw ^ ((cw >> 3) & 7);
  int srow[2], sk8[2];
#pragma unroll
  for (int i = 0; i < 2; ++i) {
    const int s = i * 512 + tid;
    const int g = s >> 6, c = s & 63;
    const int gch = c ^ ((c >> 3) & 7);
    srow[i] = g * 16 + (gch >> 2);
    sk8[i] = gch & 3;
  }

  const int NT = K >> 5;

#define STAGE_A(t)                                                            \
  {                                                                           \
    const int _b = (t) % 3;                                                   \
    const int _kb = (t) << 5;                                                 \
    _Pragma("unroll") for (int i = 0; i < 2; ++i) {                           \
      u16* ga = const_cast<u16*>(A) + (size_t)(row0 + srow[i]) * K + _kb +    \
                sk8[i] * 8;                                                   \
      __builtin_amdgcn_global_load_lds(                                       \
          (__attribute__((address_space(1))) void*)ga,                        \
          (__attribute__((address_space(3))) void*)&lds[_b][0]                \
              [(i * 512 + wid * 64) * 8], 16, 0, 0);                          \
    }                                                                         \
  }
#define STAGE_B(t)                                                            \
  {                                                                           \
    const int _b = (t) % 3;                                                   \
    const int _kb = (t) << 5;                                                 \
    _Pragma("unroll") for (int i = 0; i < 2; ++i) {                           \
      u16* gb = const_cast<u16*>(B) + (size_t)(col0 + srow[i]) * K + _kb +    \
                sk8[i] * 8;                                                   \
      __builtin_amdgcn_global_load_lds(                                       \
          (__attribute__((address_space(1))) void*)gb,                        \
          (__attribute__((address_space(3))) void*)&lds[_b][1]                \
              [(i * 512 + wid * 64) * 8], 16, 0, 0);                          \
    }                                                                         \
  }

  f32x4 acc[8][4] = {};

  STAGE_A(0); STAGE_B(0);
  STAGE_A(1); STAGE_B(1);
  asm volatile("s_waitcnt vmcnt(4)" ::: "memory");
  __builtin_amdgcn_s_barrier();

  for (int t = 0; t < NT; ++t) {
    const int buf = t % 3;
    // ---------------- phase 0
    bf16x8 a0[4], b0[4];
#pragma unroll
    for (int m = 0; m < 4; ++m)
      a0[m] = *(const bf16x8*)&lds[buf][0][((wr * 8 + m) * 64 + slot) * 8];
#pragma unroll
    for (int n = 0; n < 4; ++n)
      b0[n] = *(const bf16x8*)&lds[buf][1][((wc * 4 + n) * 64 + slot) * 8];
    if (t + 2 < NT) STAGE_A(t + 2);
    __builtin_amdgcn_s_barrier();
    asm volatile("s_waitcnt lgkmcnt(0)" ::: "memory");
    __builtin_amdgcn_sched_barrier(0);
    __builtin_amdgcn_s_setprio(1);
#pragma unroll
    for (int m = 0; m < 4; ++m)
#pragma unroll
      for (int n = 0; n < 4; ++n)
        acc[m][n] = __builtin_amdgcn_mfma_f32_16x16x32_bf16(a0[m], b0[n], acc[m][n], 0, 0, 0);
    __builtin_amdgcn_s_setprio(0);
    __builtin_amdgcn_s_barrier();
    // ---------------- phase 1 (B reused in registers)
    bf16x8 a1[4];
#pragma unroll
    for (int m = 0; m < 4; ++m)
      a1[m] = *(const bf16x8*)&lds[buf][0][((wr * 8 + 4 + m) * 64 + slot) * 8];
    if (t + 2 < NT) STAGE_B(t + 2);
    __builtin_amdgcn_s_barrier();
    asm volatile("s_waitcnt lgkmcnt(0)" ::: "memory");
    __builtin_amdgcn_sched_barrier(0);
    __builtin_amdgcn_s_setprio(1);
#pragma unroll
    for (int m = 0; m < 4; ++m)
#pragma unroll
      for (int n = 0; n < 4; ++n)
        acc[4 + m][n] = __builtin_amdgcn_mfma_f32_16x16x32_bf16(a1[m], b0[n], acc[4 + m][n], 0, 0, 0);
    __builtin_amdgcn_s_setprio(0);
    // wait for tile t+1 residency AFTER MFMA (loads finish under compute);
    // barrier below still precedes next tile's ds_reads -> same guarantee
    if (t + 2 < NT) {
      asm volatile("s_waitcnt vmcnt(4)" ::: "memory");
    } else if (t + 1 < NT) {
      asm volatile("s_waitcnt vmcnt(0)" ::: "memory");
    }
    __builtin_amdgcn_s_barrier();
  }
#undef STAGE_A
#undef STAGE_B

#pragma unroll
  for (int m = 0; m < 8; ++m) {
#pragma unroll
    for (int n = 0; n < 4; ++n) {
      const int col = col0 + wc * 64 + n * 16 + rr;
      const float bs = bias[col];
#pragma unroll
      for (int j = 0; j < 4; ++j) {
        const int row = row0 + wr * 128 + m * 16 + (lane >> 4) * 4 + j;
        outB[(size_t)row * N + col] = f2bf(acc[m][n][j] + bs);
      }
    }
  }
}

// -------------------------------------------------------------- 128^2 GEMM
template <int MODE>
__global__ __launch_bounds__(256) void gemm_bf16_kernel(
    const u16* __restrict__ A, const u16* __restrict__ B,
    const int M, const int N, const int K,
    const float* __restrict__ bias,
    u16* __restrict__ outB, float* __restrict__ outF,
    const int* __restrict__ lens, const float* __restrict__ semb,
    const float* __restrict__ pos) {
  __shared__ __align__(16) u16 As[128 * 32];
  __shared__ __align__(16) u16 Bs[128 * 32];
  const int tid = threadIdx.x;
  const int wave = tid >> 6;
  const int lane = tid & 63;
  const int row0 = blockIdx.y * 128;
  const int col0 = blockIdx.x * 128;
  const int wm = (wave >> 1) * 64;
  const int wn = (wave & 1) * 64;
  const int gch = lane ^ ((lane >> 3) & 7);
  const int sr = gch >> 2;
  const int sc = (gch & 3) * 8;
  const int rr = lane & 15;
  const int kg = lane >> 4;
  const int cwant = rr * 4 + kg;
  const int slot = cwant ^ ((cwant >> 3) & 7);
  f32x4 acc[4][4] = {};

  for (int k0 = 0; k0 < K; k0 += 32) {
    __syncthreads();
#pragma unroll
    for (int t = 0; t < 2; ++t) {
      const int li = wave * 2 + t;
      u16* ga = const_cast<u16*>(A) + (size_t)(row0 + li * 16 + sr) * K + (k0 + sc);
      u16* gb = const_cast<u16*>(B) + (size_t)(col0 + li * 16 + sr) * K + (k0 + sc);
      __builtin_amdgcn_global_load_lds(
          (__attribute__((address_space(1))) void*)ga,
          (__attribute__((address_space(3))) void*)(As + li * 512), 16, 0, 0);
      __builtin_amdgcn_global_load_lds(
          (__attribute__((address_space(1))) void*)gb,
          (__attribute__((address_space(3))) void*)(Bs + li * 512), 16, 0, 0);
    }
    __syncthreads();
    bf16x8 af[4], bfr[4];
#pragma unroll
    for (int m = 0; m < 4; ++m)
      af[m] = *(const bf16x8*)(As + ((wm >> 4) + m) * 512 + slot * 8);
#pragma unroll
    for (int n = 0; n < 4; ++n)
      bfr[n] = *(const bf16x8*)(Bs + ((wn >> 4) + n) * 512 + slot * 8);
#pragma unroll
    for (int m = 0; m < 4; ++m)
#pragma unroll
      for (int n = 0; n < 4; ++n)
        acc[m][n] = __builtin_amdgcn_mfma_f32_16x16x32_bf16(af[m], bfr[n], acc[m][n], 0, 0, 0);
  }

  const int rg = (lane >> 4) * 4;
#pragma unroll
  for (int m = 0; m < 4; ++m) {
#pragma unroll
    for (int n = 0; n < 4; ++n) {
      const int col = col0 + wn + n * 16 + rr;
#pragma unroll
      for (int j = 0; j < 4; ++j) {
        const int row = row0 + wm + m * 16 + rg + j;
        float v = acc[m][n][j];
        if (MODE == 2) {
          const int len = lens[row];
          float val = 0.f;
          if (len > 0) {
            const int si = len < 1023 ? len : 1023;
            val = v + bias[col] + semb[(size_t)si * DM + col];
          }
          val += pos[(size_t)(row & (MAXC - 1)) * DM + col];
          outB[(size_t)row * N + col] = f2bf(val);
        } else if (MODE == 3) {
          float z = v + bias[col];
          float gel = 0.5f * z * (1.f + erff(z * 0.70710678118654752440f));
          outB[(size_t)row * N + col] = f2bf(gel);
        } else {
          outF[(size_t)row * N + col] = v + bias[col];
        }
      }
    }
  }
}

// ----------------------------------------------------- chunk attention v3
// 8 waves per block, one (b,c,h) unit per wave (heads fastest -> co-resident
// waves share qkv rows). NO barriers anywhere. L<=16 (93% of chunks):
// all-register path (4 MFMA, direct max, shfl-broadcast g). L>16: per-wave
// 4KB LDS g-region, wave-local (no __syncthreads needed).
__global__ __launch_bounds__(512, 4) void chunk_attn_kernel(
    const u16* __restrict__ qkv, const int* __restrict__ nchunks,
    const int* __restrict__ starts, const int* __restrict__ lens,
    u16* __restrict__ pooled) {
  __shared__ float g_lds[8][SEQ];  // 32KB, one row per wave
  const int tid = threadIdx.x;
  const int wid = tid >> 6;
  const int lane = tid & 63;
  const int unit = blockIdx.x * 8 + wid;   // (b,c,h), h fastest
  const int h = unit % NHEAD;
  const int bc = unit / NHEAD;
  const int c = bc & (MAXC - 1);
  const int b = bc >> 8;

  const int nc = min(nchunks[b], MAXC);
  u16* prow = pooled + ((size_t)(b * MAXC + c)) * DM + h * DHEAD;
  if (c >= nc) {  // empty chunk: pooled ctx = 0 (no barriers in kernel)
    U2 z; z.x = 0; z.y = 0;
    *(U2*)(prow + lane * 2) = z;
    return;
  }
  const int s0 = starts[b * (MAXC + 1) + c];
  const int L = lens[b * MAXC + c];
  const u16* Qb = qkv + ((size_t)(b * SEQ + s0)) * QKVN + h * DHEAD;
  const u16* Kb = Qb + DM;
  const u16* Vb = Qb + 2 * DM;

  const int col = lane & 15;   // key col of D; also frag row index
  const int grp = lane >> 4;
  const float scale = 0.08838834764831845f;  // 1/sqrt(128)

  float a0 = 0.f, a1 = 0.f;

  if (L <= 16) {
    // ---------------- register-only single-tile path
    const int rc = col < L ? col : (L - 1);  // clamped Q/K row
    bf16x8 qf[4], kf[4];
#pragma unroll
    for (int s = 0; s < 4; ++s) {
      qf[s] = *(const bf16x8*)(Qb + (size_t)rc * QKVN + s * 32 + grp * 8);
      kf[s] = *(const bf16x8*)(Kb + (size_t)rc * QKVN + s * 32 + grp * 8);
    }
    f32x4 sc = {0.f, 0.f, 0.f, 0.f};
#pragma unroll
    for (int s = 0; s < 4; ++s)
      sc = __builtin_amdgcn_mfma_f32_16x16x32_bf16(qf[s], kf[s], sc, 0, 0, 0);
    const bool kvalid = col < L;
    float g = 0.f;
#pragma unroll
    for (int j = 0; j < 4; ++j) {
      float sj = sc[j] * scale;
      float mv = kvalid ? sj : -3e38f;
      mv = fmaxf(mv, __shfl_xor(mv, 1));
      mv = fmaxf(mv, __shfl_xor(mv, 2));
      mv = fmaxf(mv, __shfl_xor(mv, 4));
      mv = fmaxf(mv, __shfl_xor(mv, 8));
      float pv = kvalid ? __expf(sj - mv) : 0.f;
      float dv = pv;
      dv += __shfl_xor(dv, 1);
      dv += __shfl_xor(dv, 2);
      dv += __shfl_xor(dv, 4);
      dv += __shfl_xor(dv, 8);
      const bool rv = (grp * 4 + j) < L;   // row validity
      g += rv ? pv / dv : 0.f;
    }
    g += __shfl_xor(g, 16);
    g += __shfl_xor(g, 32);   // every lane: column sum for col=lane&15
    for (int j = 0; j < L; ++j) {
      float gj = __shfl(g, j);             // lane j holds g[col=j]
      U2 vv = *(const U2*)(Vb + (size_t)j * QKVN + lane * 2);
      a0 += gj * bf2f(vv.x);
      a1 += gj * bf2f(vv.y);
    }
  } else {
    // ---------------- general tiled path (wave-local LDS g, no barriers)
    float* gw = g_lds[wid];
    for (int j = lane; j < L; j += 64) gw[j] = 0.f;
    const int NT = (L + 15) >> 4;
    for (int qt = 0; qt < NT; ++qt) {
      const int qr = qt * 16 + col;
      const int qrc = qr < L ? qr : (L - 1);
      bf16x8 qf[4];
#pragma unroll
      for (int s = 0; s < 4; ++s)
        qf[s] = *(const bf16x8*)(Qb + (size_t)qrc * QKVN + s * 32 + grp * 8);

      float m[4] = {-3e38f, -3e38f, -3e38f, -3e38f};
      float den[4] = {0.f, 0.f, 0.f, 0.f};
      for (int kt = 0; kt < NT; ++kt) {
        const int kr = kt * 16 + col;
        const bool kvalid = kr < L;
        const int krc = kvalid ? kr : (L - 1);
        f32x4 sc = {0.f, 0.f, 0.f, 0.f};
#pragma unroll
        for (int s = 0; s < 4; ++s) {
          bf16x8 kf = *(const bf16x8*)(Kb + (size_t)krc * QKVN + s * 32 + grp * 8);
          sc = __builtin_amdgcn_mfma_f32_16x16x32_bf16(qf[s], kf, sc, 0, 0, 0);
        }
#pragma unroll
        for (int j = 0; j < 4; ++j) {
          float sj = sc[j] * scale;
          float mv = kvalid ? sj : -3e38f;
          mv = fmaxf(mv, __shfl_xor(mv, 1));
          mv = fmaxf(mv, __shfl_xor(mv, 2));
          mv = fmaxf(mv, __shfl_xor(mv, 4));
          mv = fmaxf(mv, __shfl_xor(mv, 8));
          float mn = fmaxf(m[j], mv);
          float pv = kvalid ? __expf(sj - mn) : 0.f;
          pv += __shfl_xor(pv, 1);
          pv += __shfl_xor(pv, 2);
          pv += __shfl_xor(pv, 4);
          pv += __shfl_xor(pv, 8);
          den[j] = den[j] * __expf(m[j] - mn) + pv;
          m[j] = mn;
        }
      }
      float inv[4];
#pragma unroll
      for (int j = 0; j < 4; ++j) {
        const bool rv = (qt * 16 + grp * 4 + j) < L;
        inv[j] = rv ? 1.f / den[j] : 0.f;
      }
      for (int kt = 0; kt < NT; ++kt) {
        const int kr = kt * 16 + col;
        const bool kvalid = kr < L;
        const int krc = kvalid ? kr : (L - 1);
        f32x4 sc = {0.f, 0.f, 0.f, 0.f};
#pragma unroll
        for (int s = 0; s < 4; ++s) {
          bf16x8 kf = *(const bf16x8*)(Kb + (size_t)krc * QKVN + s * 32 + grp * 8);
          sc = __builtin_amdgcn_mfma_f32_16x16x32_bf16(qf[s], kf, sc, 0, 0, 0);
        }
        float colsum = 0.f;
#pragma unroll
        for (int j = 0; j < 4; ++j)
          colsum += __expf(sc[j] * scale - m[j]) * inv[j];
        colsum += __shfl_xor(colsum, 16);
        colsum += __shfl_xor(colsum, 32);
        if (grp == 0 && kvalid) gw[kt * 16 + col] += colsum;
      }
    }
    for (int j = 0; j < L; ++j) {
      float gj = gw[j];
      U2 vv = *(const U2*)(Vb + (size_t)j * QKVN + lane * 2);
      a0 += gj * bf2f(vv.x);
      a1 += gj * bf2f(vv.y);
    }
  }
  const float invL = 1.f / (float)L;
  U2 r; r.x = f2bf(a0 * invL); r.y = f2bf(a1 * invL);
  *(U2*)(prow + lane * 2) = r;
}

// ---------------------------------------------------------------- LayerNorm
__global__ __launch_bounds__(256) void ln_kernel(
    const float* __restrict__ h2, const float* __restrict__ gamma,
    const float* __restrict__ beta, float* __restrict__ out) {
  const int row = blockIdx.x;
  const float* x = h2 + (size_t)row * DM;
  float* o = out + (size_t)row * DM;
  const int tid = threadIdx.x;
  float v[6];
  float s = 0.f;
#pragma unroll
  for (int i = 0; i < 6; ++i) { v[i] = x[tid + i * 256]; s += v[i]; }
  __shared__ float red[8];
#pragma unroll
  for (int off = 32; off; off >>= 1) s += __shfl_xor(s, off);
  if ((tid & 63) == 0) red[tid >> 6] = s;
  __syncthreads();
  const float mu = (red[0] + red[1] + red[2] + red[3]) * (1.f / (float)DM);
  float vs = 0.f;
#pragma unroll
  for (int i = 0; i < 6; ++i) { float d = v[i] - mu; vs += d * d; }
#pragma unroll
  for (int off = 32; off; off >>= 1) vs += __shfl_xor(vs, off);
  __shared__ float red2[8];
  if ((tid & 63) == 0) red2[tid >> 6] = vs;
  __syncthreads();
  const float var = (red2[0] + red2[1] + red2[2] + red2[3]) * (1.f / (float)DM);
  const float inv = rsqrtf(var + 1e-5f);
#pragma unroll
  for (int i = 0; i < 6; ++i) {
    const int cidx = tid + i * 256;
    o[cidx] = (v[i] - mu) * inv * gamma[cidx] + beta[cidx];
  }
}

// ------------------------------------------------------------------ launch
extern "C" void kernel_launch(void* const* d_in, const int* in_sizes, int n_in,
                              void* d_out, int out_size, void* d_ws, size_t ws_size,
                              hipStream_t stream) {
  const float* x    = (const float*)d_in[0];
  const float* bnd  = (const float*)d_in[1];
  const float* wqkv = (const float*)d_in[2];
  const float* bqkv = (const float*)d_in[3];
  const float* wout = (const float*)d_in[4];
  const float* bout = (const float*)d_in[5];
  const float* w1   = (const float*)d_in[6];
  const float* b1   = (const float*)d_in[7];
  const float* w2   = (const float*)d_in[8];
  const float* b2   = (const float*)d_in[9];
  const float* lng  = (const float*)d_in[10];
  const float* lnb  = (const float*)d_in[11];
  const float* pos  = (const float*)d_in[12];
  const float* semb = (const float*)d_in[13];
  float* out = (float*)d_out;

  char* ws = (char*)d_ws;
  size_t off = 0;
  auto alloc = [&](size_t bytes) -> char* {
    char* p = ws + off;
    off += (bytes + 255) & ~(size_t)255;
    return p;
  };
  u16* x_bf    = (u16*)alloc((size_t)NB * SEQ * DM * 2);
  u16* wqkv_bf = (u16*)alloc((size_t)3 * DM * DM * 2);
  u16* wout_bf = (u16*)alloc((size_t)DM * DM * 2);
  u16* w1_bf   = (u16*)alloc((size_t)2 * DM * DM * 2);
  u16* w2_bf   = (u16*)alloc((size_t)2 * DM * DM * 2);
  u16* qkv_bf  = (u16*)alloc((size_t)NB * SEQ * QKVN * 2);
  int* nchunks = (int*)alloc(NB * 4);
  int* starts  = (int*)alloc(NB * (MAXC + 1) * 4);
  int* lens    = (int*)alloc(NB * MAXC * 4);
  u16* pooled  = (u16*)alloc((size_t)NB * MAXC * DM * 2);
  u16* chunks  = (u16*)alloc((size_t)NB * MAXC * DM * 2);
  u16* h1      = (u16*)alloc((size_t)NB * MAXC * 2 * DM * 2);
  float* h2    = (float*)alloc((size_t)NB * MAXC * DM * 4);
  (void)ws_size; (void)in_sizes; (void)n_in; (void)out_size;

  cvt5_bf16_kernel<<<2048, 256, 0, stream>>>(
      x, x_bf, NB * SEQ * DM / 4,
      wqkv, wqkv_bf, 3 * DM * DM / 4,
      wout, wout_bf, DM * DM / 4,
      w1, w1_bf, 2 * DM * DM / 4,
      w2, w2_bf, 2 * DM * DM / 4);

  segment_kernel<<<NB, 64, 0, stream>>>(bnd, nchunks, starts, lens);

  gemm256_kernel<<<(NB * SEQ / 256) * (QKVN / 256), 512, 0, stream>>>(
      x_bf, wqkv_bf, NB * SEQ, QKVN, DM, bqkv, qkv_bf);

  // per-chunk attention: 24576 units, 8 per block
  chunk_attn_kernel<<<NB * MAXC * NHEAD / 8, 512, 0, stream>>>(
      qkv_bf, nchunks, starts, lens, pooled);

  gemm_bf16_kernel<2><<<dim3(DM / 128, NB * MAXC / 128), 256, 0, stream>>>(
      pooled, wout_bf, NB * MAXC, DM, DM, bout, chunks, nullptr, lens, semb, pos);

  gemm_bf16_kernel<3><<<dim3(2 * DM / 128, NB * MAXC / 128), 256, 0, stream>>>(
      chunks, w1_bf, NB * MAXC, 2 * DM, DM, b1, h1, nullptr, nullptr, nullptr, nullptr);

  gemm_bf16_kernel<4><<<dim3(DM / 128, NB * MAXC / 128), 256, 0, stream>>>(
      h1, w2_bf, NB * MAXC, DM, 2 * DM, b2, nullptr, h2, nullptr, nullptr, nullptr);

  ln_kernel<<<NB * MAXC, 256, 0, stream>>>(h2, lng, lnb, out);
}

// Round 7
// 396.450 us; speedup vs baseline: 1.0527x; 1.0527x over previous
//
#include <hip/hip_runtime.h>
#include <math.h>

// Problem constants
#define NB 8
#define SEQ 1024
#define DM 1536
#define NHEAD 12
#define DHEAD 128
#define MAXC 256
#define QKVN 4608
#define THRESH 0.85f

typedef unsigned short u16;
typedef __attribute__((ext_vector_type(8))) __bf16 bf16x8;
typedef __attribute__((ext_vector_type(4))) float f32x4;

struct __align__(4) U2 { u16 x, y; };
struct __align__(8) U4 { u16 x, y, z, w; };

__device__ __forceinline__ float bf2f(u16 u) {
  union { unsigned i; float f; } c; c.i = ((unsigned)u) << 16; return c.f;
}
__device__ __forceinline__ u16 f2bf(float f) {
  union { float f; unsigned i; } c; c.f = f;
  unsigned r = c.i + 0x7FFFu + ((c.i >> 16) & 1u);  // RNE
  return (u16)(r >> 16);
}

// ---------------------------------------------------------------- converts
__global__ __launch_bounds__(256) void cvt5_bf16_kernel(
    const float* __restrict__ i0, u16* __restrict__ o0, int n0,
    const float* __restrict__ i1, u16* __restrict__ o1, int n1,
    const float* __restrict__ i2, u16* __restrict__ o2, int n2,
    const float* __restrict__ i3, u16* __restrict__ o3, int n3,
    const float* __restrict__ i4, u16* __restrict__ o4, int n4) {
  const int stride = gridDim.x * blockDim.x;
  const int t0 = blockIdx.x * blockDim.x + threadIdx.x;
  const float* ins[5] = {i0, i1, i2, i3, i4};
  u16* outs[5] = {o0, o1, o2, o3, o4};
  const int ns[5] = {n0, n1, n2, n3, n4};
#pragma unroll
  for (int a = 0; a < 5; ++a) {
    const float* in = ins[a];
    u16* out = outs[a];
    for (int i = t0; i < ns[a]; i += stride) {
      float4 f = ((const float4*)in)[i];
      U4 u; u.x = f2bf(f.x); u.y = f2bf(f.y); u.z = f2bf(f.z); u.w = f2bf(f.w);
      ((U4*)out)[i] = u;
    }
  }
}

// ------------------------------------------------------------- segmentation
__global__ __launch_bounds__(64) void segment_kernel(
    const float* __restrict__ bnd, int* __restrict__ nchunks,
    int* __restrict__ starts, int* __restrict__ lens) {
  const int b = blockIdx.x;
  const int lane = threadIdx.x;
  int running = 0;
  for (int g = 0; g < SEQ / 64; ++g) {
    int s = g * 64 + lane;
    bool isb = bnd[b * SEQ + s] > THRESH;
    unsigned long long mask = __ballot(isb ? 1 : 0);
    int excl = __popcll(mask & ((1ULL << lane) - 1ULL));
    if (isb) {
      int c = running + excl;
      if (c <= MAXC) starts[b * (MAXC + 1) + c] = s;
    }
    running += __popcll(mask);
  }
  if (lane == 0) nchunks[b] = running;
  __syncthreads();
  int ncl = min(running, MAXC);
  for (int c = lane; c < MAXC; c += 64) {
    int v = 0;
    if (c < ncl) {
      int st = starts[b * (MAXC + 1) + c];
      int en = (c + 1 < running) ? starts[b * (MAXC + 1) + c + 1] : SEQ;
      v = en - st;
    }
    lens[b * MAXC + c] = v;
  }
}

// --------------------------------------------------- 256x256 pipelined GEMM
// Single phase per K-tile (BK=32): read 12 frags, stage t+2, one barrier,
// 32-MFMA cluster, counted vmcnt(4). 3 LDS buffers, prefetch distance 2.
__global__ __launch_bounds__(512, 2) void gemm256_kernel(
    const u16* __restrict__ A, const u16* __restrict__ B,
    const int M, const int N, const int K,
    const float* __restrict__ bias, u16* __restrict__ outB) {
  __shared__ __align__(16) u16 lds[3][2][8192];  // [buf][A/B][1024 slots * 8]
  const int tid = threadIdx.x;
  const int wid = tid >> 6;
  const int lane = tid & 63;
  const int cpx = gridDim.x >> 3;
  const int bid = ((int)blockIdx.x & 7) * cpx + ((int)blockIdx.x >> 3);
  const int NX = N >> 8;
  const int row0 = (bid / NX) << 8;
  const int col0 = (bid % NX) << 8;

  const int wr = wid >> 2;
  const int wc = wid & 3;
  const int rr = lane & 15;
  const int kg = lane >> 4;
  const int cw = rr * 4 + kg;
  const int slot = cw ^ ((cw >> 3) & 7);
  int srow[2], sk8[2];
#pragma unroll
  for (int i = 0; i < 2; ++i) {
    const int s = i * 512 + tid;
    const int g = s >> 6, c = s & 63;
    const int gch = c ^ ((c >> 3) & 7);
    srow[i] = g * 16 + (gch >> 2);
    sk8[i] = gch & 3;
  }

  const int NT = K >> 5;

#define STAGE_A(t)                                                            \
  {                                                                           \
    const int _b = (t) % 3;                                                   \
    const int _kb = (t) << 5;                                                 \
    _Pragma("unroll") for (int i = 0; i < 2; ++i) {                           \
      u16* ga = const_cast<u16*>(A) + (size_t)(row0 + srow[i]) * K + _kb +    \
                sk8[i] * 8;                                                   \
      __builtin_amdgcn_global_load_lds(                                       \
          (__attribute__((address_space(1))) void*)ga,                        \
          (__attribute__((address_space(3))) void*)&lds[_b][0]                \
              [(i * 512 + wid * 64) * 8], 16, 0, 0);                          \
    }                                                                         \
  }
#define STAGE_B(t)                                                            \
  {                                                                           \
    const int _b = (t) % 3;                                                   \
    const int _kb = (t) << 5;                                                 \
    _Pragma("unroll") for (int i = 0; i < 2; ++i) {                           \
      u16* gb = const_cast<u16*>(B) + (size_t)(col0 + srow[i]) * K + _kb +    \
                sk8[i] * 8;                                                   \
      __builtin_amdgcn_global_load_lds(                                       \
          (__attribute__((address_space(1))) void*)gb,                        \
          (__attribute__((address_space(3))) void*)&lds[_b][1]                \
              [(i * 512 + wid * 64) * 8], 16, 0, 0);                          \
    }                                                                         \
  }

  f32x4 acc[8][4] = {};

  STAGE_A(0); STAGE_B(0);
  STAGE_A(1); STAGE_B(1);
  asm volatile("s_waitcnt vmcnt(4)" ::: "memory");
  __builtin_amdgcn_s_barrier();

  for (int t = 0; t < NT; ++t) {
    const int buf = t % 3;
    bf16x8 af[8], bf[4];
#pragma unroll
    for (int m = 0; m < 8; ++m)
      af[m] = *(const bf16x8*)&lds[buf][0][((wr * 8 + m) * 64 + slot) * 8];
#pragma unroll
    for (int n = 0; n < 4; ++n)
      bf[n] = *(const bf16x8*)&lds[buf][1][((wc * 4 + n) * 64 + slot) * 8];
    if (t + 2 < NT) { STAGE_A(t + 2); STAGE_B(t + 2); }
    __builtin_amdgcn_s_barrier();
    asm volatile("s_waitcnt lgkmcnt(0)" ::: "memory");
    __builtin_amdgcn_sched_barrier(0);
    __builtin_amdgcn_s_setprio(1);
#pragma unroll
    for (int m = 0; m < 8; ++m)
#pragma unroll
      for (int n = 0; n < 4; ++n)
        acc[m][n] = __builtin_amdgcn_mfma_f32_16x16x32_bf16(af[m], bf[n], acc[m][n], 0, 0, 0);
    __builtin_amdgcn_s_setprio(0);
    // counted wait: leaves t+2's 4 loads in flight, guarantees t+1 resident
    if (t + 2 < NT) {
      asm volatile("s_waitcnt vmcnt(4)" ::: "memory");
    } else if (t + 1 < NT) {
      asm volatile("s_waitcnt vmcnt(0)" ::: "memory");
    }
    __builtin_amdgcn_s_barrier();
  }
#undef STAGE_A
#undef STAGE_B

#pragma unroll
  for (int m = 0; m < 8; ++m) {
#pragma unroll
    for (int n = 0; n < 4; ++n) {
      const int col = col0 + wc * 64 + n * 16 + rr;
      const float bs = bias[col];
#pragma unroll
      for (int j = 0; j < 4; ++j) {
        const int row = row0 + wr * 128 + m * 16 + (lane >> 4) * 4 + j;
        outB[(size_t)row * N + col] = f2bf(acc[m][n][j] + bs);
      }
    }
  }
}

// -------------------------------------------------------------- 128^2 GEMM
template <int MODE>
__global__ __launch_bounds__(256) void gemm_bf16_kernel(
    const u16* __restrict__ A, const u16* __restrict__ B,
    const int M, const int N, const int K,
    const float* __restrict__ bias,
    u16* __restrict__ outB, float* __restrict__ outF,
    const int* __restrict__ lens, const float* __restrict__ semb,
    const float* __restrict__ pos) {
  __shared__ __align__(16) u16 As[128 * 32];
  __shared__ __align__(16) u16 Bs[128 * 32];
  const int tid = threadIdx.x;
  const int wave = tid >> 6;
  const int lane = tid & 63;
  const int row0 = blockIdx.y * 128;
  const int col0 = blockIdx.x * 128;
  const int wm = (wave >> 1) * 64;
  const int wn = (wave & 1) * 64;
  const int gch = lane ^ ((lane >> 3) & 7);
  const int sr = gch >> 2;
  const int sc = (gch & 3) * 8;
  const int rr = lane & 15;
  const int kg = lane >> 4;
  const int cwant = rr * 4 + kg;
  const int slot = cwant ^ ((cwant >> 3) & 7);
  f32x4 acc[4][4] = {};

  for (int k0 = 0; k0 < K; k0 += 32) {
    __syncthreads();
#pragma unroll
    for (int t = 0; t < 2; ++t) {
      const int li = wave * 2 + t;
      u16* ga = const_cast<u16*>(A) + (size_t)(row0 + li * 16 + sr) * K + (k0 + sc);
      u16* gb = const_cast<u16*>(B) + (size_t)(col0 + li * 16 + sr) * K + (k0 + sc);
      __builtin_amdgcn_global_load_lds(
          (__attribute__((address_space(1))) void*)ga,
          (__attribute__((address_space(3))) void*)(As + li * 512), 16, 0, 0);
      __builtin_amdgcn_global_load_lds(
          (__attribute__((address_space(1))) void*)gb,
          (__attribute__((address_space(3))) void*)(Bs + li * 512), 16, 0, 0);
    }
    __syncthreads();
    bf16x8 af[4], bfr[4];
#pragma unroll
    for (int m = 0; m < 4; ++m)
      af[m] = *(const bf16x8*)(As + ((wm >> 4) + m) * 512 + slot * 8);
#pragma unroll
    for (int n = 0; n < 4; ++n)
      bfr[n] = *(const bf16x8*)(Bs + ((wn >> 4) + n) * 512 + slot * 8);
#pragma unroll
    for (int m = 0; m < 4; ++m)
#pragma unroll
      for (int n = 0; n < 4; ++n)
        acc[m][n] = __builtin_amdgcn_mfma_f32_16x16x32_bf16(af[m], bfr[n], acc[m][n], 0, 0, 0);
  }

  const int rg = (lane >> 4) * 4;
#pragma unroll
  for (int m = 0; m < 4; ++m) {
#pragma unroll
    for (int n = 0; n < 4; ++n) {
      const int col = col0 + wn + n * 16 + rr;
#pragma unroll
      for (int j = 0; j < 4; ++j) {
        const int row = row0 + wm + m * 16 + rg + j;
        float v = acc[m][n][j];
        if (MODE == 2) {
          const int len = lens[row];
          float val = 0.f;
          if (len > 0) {
            const int si = len < 1023 ? len : 1023;
            val = v + bias[col] + semb[(size_t)si * DM + col];
          }
          val += pos[(size_t)(row & (MAXC - 1)) * DM + col];
          outB[(size_t)row * N + col] = f2bf(val);
        } else if (MODE == 3) {
          float z = v + bias[col];
          float gel = 0.5f * z * (1.f + erff(z * 0.70710678118654752440f));
          outB[(size_t)row * N + col] = f2bf(gel);
        } else {
          outF[(size_t)row * N + col] = v + bias[col];
        }
      }
    }
  }
}

// ----------------------------------------------------- chunk attention v4
// v3 math (register-only L<=16 fast path, 4 MFMA, no barriers) + v2 launch
// (one 64-thread wave per block -> high wave occupancy). L>16: LDS g only.
__global__ __launch_bounds__(64) void chunk_attn_kernel(
    const u16* __restrict__ qkv, const int* __restrict__ nchunks,
    const int* __restrict__ starts, const int* __restrict__ lens,
    u16* __restrict__ pooled) {
  __shared__ float g_lds[SEQ];
  const int h = blockIdx.x;
  const int c = blockIdx.y;
  const int b = blockIdx.z;
  const int lane = threadIdx.x;
  const int nc = min(nchunks[b], MAXC);
  u16* prow = pooled + ((size_t)(b * MAXC + c)) * DM + h * DHEAD;
  if (c >= nc) {  // empty chunk: pooled ctx = 0
    U2 z; z.x = 0; z.y = 0;
    *(U2*)(prow + lane * 2) = z;
    return;
  }
  const int s0 = starts[b * (MAXC + 1) + c];
  const int L = lens[b * MAXC + c];
  const u16* Qb = qkv + ((size_t)(b * SEQ + s0)) * QKVN + h * DHEAD;
  const u16* Kb = Qb + DM;
  const u16* Vb = Qb + 2 * DM;

  const int col = lane & 15;
  const int grp = lane >> 4;
  const float scale = 0.08838834764831845f;  // 1/sqrt(128)

  float a0 = 0.f, a1 = 0.f;

  if (L <= 16) {
    // ---------------- register-only single-tile path
    const int rc = col < L ? col : (L - 1);
    bf16x8 qf[4], kf[4];
#pragma unroll
    for (int s = 0; s < 4; ++s) {
      qf[s] = *(const bf16x8*)(Qb + (size_t)rc * QKVN + s * 32 + grp * 8);
      kf[s] = *(const bf16x8*)(Kb + (size_t)rc * QKVN + s * 32 + grp * 8);
    }
    f32x4 sc = {0.f, 0.f, 0.f, 0.f};
#pragma unroll
    for (int s = 0; s < 4; ++s)
      sc = __builtin_amdgcn_mfma_f32_16x16x32_bf16(qf[s], kf[s], sc, 0, 0, 0);
    const bool kvalid = col < L;
    float g = 0.f;
#pragma unroll
    for (int j = 0; j < 4; ++j) {
      float sj = sc[j] * scale;
      float mv = kvalid ? sj : -3e38f;
      mv = fmaxf(mv, __shfl_xor(mv, 1));
      mv = fmaxf(mv, __shfl_xor(mv, 2));
      mv = fmaxf(mv, __shfl_xor(mv, 4));
      mv = fmaxf(mv, __shfl_xor(mv, 8));
      float pv = kvalid ? __expf(sj - mv) : 0.f;
      float dv = pv;
      dv += __shfl_xor(dv, 1);
      dv += __shfl_xor(dv, 2);
      dv += __shfl_xor(dv, 4);
      dv += __shfl_xor(dv, 8);
      const bool rv = (grp * 4 + j) < L;
      g += rv ? pv / dv : 0.f;
    }
    g += __shfl_xor(g, 16);
    g += __shfl_xor(g, 32);
    for (int j = 0; j < L; ++j) {
      float gj = __shfl(g, j);
      U2 vv = *(const U2*)(Vb + (size_t)j * QKVN + lane * 2);
      a0 += gj * bf2f(vv.x);
      a1 += gj * bf2f(vv.y);
    }
  } else {
    // ---------------- general tiled path
    float* gw = g_lds;
    for (int j = lane; j < L; j += 64) gw[j] = 0.f;
    const int NT = (L + 15) >> 4;
    for (int qt = 0; qt < NT; ++qt) {
      const int qr = qt * 16 + col;
      const int qrc = qr < L ? qr : (L - 1);
      bf16x8 qf[4];
#pragma unroll
      for (int s = 0; s < 4; ++s)
        qf[s] = *(const bf16x8*)(Qb + (size_t)qrc * QKVN + s * 32 + grp * 8);

      float m[4] = {-3e38f, -3e38f, -3e38f, -3e38f};
      float den[4] = {0.f, 0.f, 0.f, 0.f};
      for (int kt = 0; kt < NT; ++kt) {
        const int kr = kt * 16 + col;
        const bool kvalid = kr < L;
        const int krc = kvalid ? kr : (L - 1);
        f32x4 sc = {0.f, 0.f, 0.f, 0.f};
#pragma unroll
        for (int s = 0; s < 4; ++s) {
          bf16x8 kf = *(const bf16x8*)(Kb + (size_t)krc * QKVN + s * 32 + grp * 8);
          sc = __builtin_amdgcn_mfma_f32_16x16x32_bf16(qf[s], kf, sc, 0, 0, 0);
        }
#pragma unroll
        for (int j = 0; j < 4; ++j) {
          float sj = sc[j] * scale;
          float mv = kvalid ? sj : -3e38f;
          mv = fmaxf(mv, __shfl_xor(mv, 1));
          mv = fmaxf(mv, __shfl_xor(mv, 2));
          mv = fmaxf(mv, __shfl_xor(mv, 4));
          mv = fmaxf(mv, __shfl_xor(mv, 8));
          float mn = fmaxf(m[j], mv);
          float pv = kvalid ? __expf(sj - mn) : 0.f;
          pv += __shfl_xor(pv, 1);
          pv += __shfl_xor(pv, 2);
          pv += __shfl_xor(pv, 4);
          pv += __shfl_xor(pv, 8);
          den[j] = den[j] * __expf(m[j] - mn) + pv;
          m[j] = mn;
        }
      }
      float inv[4];
#pragma unroll
      for (int j = 0; j < 4; ++j) {
        const bool rv = (qt * 16 + grp * 4 + j) < L;
        inv[j] = rv ? 1.f / den[j] : 0.f;
      }
      for (int kt = 0; kt < NT; ++kt) {
        const int kr = kt * 16 + col;
        const bool kvalid = kr < L;
        const int krc = kvalid ? kr : (L - 1);
        f32x4 sc = {0.f, 0.f, 0.f, 0.f};
#pragma unroll
        for (int s = 0; s < 4; ++s) {
          bf16x8 kf = *(const bf16x8*)(Kb + (size_t)krc * QKVN + s * 32 + grp * 8);
          sc = __builtin_amdgcn_mfma_f32_16x16x32_bf16(qf[s], kf, sc, 0, 0, 0);
        }
        float colsum = 0.f;
#pragma unroll
        for (int j = 0; j < 4; ++j)
          colsum += __expf(sc[j] * scale - m[j]) * inv[j];
        colsum += __shfl_xor(colsum, 16);
        colsum += __shfl_xor(colsum, 32);
        if (grp == 0 && kvalid) gw[kt * 16 + col] += colsum;
      }
    }
    for (int j = 0; j < L; ++j) {
      float gj = gw[j];
      U2 vv = *(const U2*)(Vb + (size_t)j * QKVN + lane * 2);
      a0 += gj * bf2f(vv.x);
      a1 += gj * bf2f(vv.y);
    }
  }
  const float invL = 1.f / (float)L;
  U2 r; r.x = f2bf(a0 * invL); r.y = f2bf(a1 * invL);
  *(U2*)(prow + lane * 2) = r;
}

// ---------------------------------------------------------------- LayerNorm
__global__ __launch_bounds__(256) void ln_kernel(
    const float* __restrict__ h2, const float* __restrict__ gamma,
    const float* __restrict__ beta, float* __restrict__ out) {
  const int row = blockIdx.x;
  const float* x = h2 + (size_t)row * DM;
  float* o = out + (size_t)row * DM;
  const int tid = threadIdx.x;
  float v[6];
  float s = 0.f;
#pragma unroll
  for (int i = 0; i < 6; ++i) { v[i] = x[tid + i * 256]; s += v[i]; }
  __shared__ float red[8];
#pragma unroll
  for (int off = 32; off; off >>= 1) s += __shfl_xor(s, off);
  if ((tid & 63) == 0) red[tid >> 6] = s;
  __syncthreads();
  const float mu = (red[0] + red[1] + red[2] + red[3]) * (1.f / (float)DM);
  float vs = 0.f;
#pragma unroll
  for (int i = 0; i < 6; ++i) { float d = v[i] - mu; vs += d * d; }
#pragma unroll
  for (int off = 32; off; off >>= 1) vs += __shfl_xor(vs, off);
  __shared__ float red2[8];
  if ((tid & 63) == 0) red2[tid >> 6] = vs;
  __syncthreads();
  const float var = (red2[0] + red2[1] + red2[2] + red2[3]) * (1.f / (float)DM);
  const float inv = rsqrtf(var + 1e-5f);
#pragma unroll
  for (int i = 0; i < 6; ++i) {
    const int cidx = tid + i * 256;
    o[cidx] = (v[i] - mu) * inv * gamma[cidx] + beta[cidx];
  }
}

// ------------------------------------------------------------------ launch
extern "C" void kernel_launch(void* const* d_in, const int* in_sizes, int n_in,
                              void* d_out, int out_size, void* d_ws, size_t ws_size,
                              hipStream_t stream) {
  const float* x    = (const float*)d_in[0];
  const float* bnd  = (const float*)d_in[1];
  const float* wqkv = (const float*)d_in[2];
  const float* bqkv = (const float*)d_in[3];
  const float* wout = (const float*)d_in[4];
  const float* bout = (const float*)d_in[5];
  const float* w1   = (const float*)d_in[6];
  const float* b1   = (const float*)d_in[7];
  const float* w2   = (const float*)d_in[8];
  const float* b2   = (const float*)d_in[9];
  const float* lng  = (const float*)d_in[10];
  const float* lnb  = (const float*)d_in[11];
  const float* pos  = (const float*)d_in[12];
  const float* semb = (const float*)d_in[13];
  float* out = (float*)d_out;

  char* ws = (char*)d_ws;
  size_t off = 0;
  auto alloc = [&](size_t bytes) -> char* {
    char* p = ws + off;
    off += (bytes + 255) & ~(size_t)255;
    return p;
  };
  u16* x_bf    = (u16*)alloc((size_t)NB * SEQ * DM * 2);
  u16* wqkv_bf = (u16*)alloc((size_t)3 * DM * DM * 2);
  u16* wout_bf = (u16*)alloc((size_t)DM * DM * 2);
  u16* w1_bf   = (u16*)alloc((size_t)2 * DM * DM * 2);
  u16* w2_bf   = (u16*)alloc((size_t)2 * DM * DM * 2);
  u16* qkv_bf  = (u16*)alloc((size_t)NB * SEQ * QKVN * 2);
  int* nchunks = (int*)alloc(NB * 4);
  int* starts  = (int*)alloc(NB * (MAXC + 1) * 4);
  int* lens    = (int*)alloc(NB * MAXC * 4);
  u16* pooled  = (u16*)alloc((size_t)NB * MAXC * DM * 2);
  u16* chunks  = (u16*)alloc((size_t)NB * MAXC * DM * 2);
  u16* h1      = (u16*)alloc((size_t)NB * MAXC * 2 * DM * 2);
  float* h2    = (float*)alloc((size_t)NB * MAXC * DM * 4);
  (void)ws_size; (void)in_sizes; (void)n_in; (void)out_size;

  cvt5_bf16_kernel<<<2048, 256, 0, stream>>>(
      x, x_bf, NB * SEQ * DM / 4,
      wqkv, wqkv_bf, 3 * DM * DM / 4,
      wout, wout_bf, DM * DM / 4,
      w1, w1_bf, 2 * DM * DM / 4,
      w2, w2_bf, 2 * DM * DM / 4);

  segment_kernel<<<NB, 64, 0, stream>>>(bnd, nchunks, starts, lens);

  gemm256_kernel<<<(NB * SEQ / 256) * (QKVN / 256), 512, 0, stream>>>(
      x_bf, wqkv_bf, NB * SEQ, QKVN, DM, bqkv, qkv_bf);

  chunk_attn_kernel<<<dim3(NHEAD, MAXC, NB), 64, 0, stream>>>(
      qkv_bf, nchunks, starts, lens, pooled);

  gemm_bf16_kernel<2><<<dim3(DM / 128, NB * MAXC / 128), 256, 0, stream>>>(
      pooled, wout_bf, NB * MAXC, DM, DM, bout, chunks, nullptr, lens, semb, pos);

  gemm_bf16_kernel<3><<<dim3(2 * DM / 128, NB * MAXC / 128), 256, 0, stream>>>(
      chunks, w1_bf, NB * MAXC, 2 * DM, DM, b1, h1, nullptr, nullptr, nullptr, nullptr);

  gemm_bf16_kernel<4><<<dim3(DM / 128, NB * MAXC / 128), 256, 0, stream>>>(
      h1, w2_bf, NB * MAXC, DM, 2 * DM, b2, nullptr, h2, nullptr, nullptr, nullptr);

  ln_kernel<<<NB * MAXC, 256, 0, stream>>>(h2, lng, lnb, out);
}

// Round 8
// 353.425 us; speedup vs baseline: 1.1809x; 1.1217x over previous
//
#include <hip/hip_runtime.h>
#include <math.h>

// Problem constants
#define NB 8
#define SEQ 1024
#define DM 1536
#define NHEAD 12
#define DHEAD 128
#define MAXC 256
#define QKVN 4608
#define THRESH 0.85f

typedef unsigned short u16;
typedef __attribute__((ext_vector_type(8))) __bf16 bf16x8;
typedef __attribute__((ext_vector_type(4))) float f32x4;

struct __align__(4) U2 { u16 x, y; };
struct __align__(8) U4 { u16 x, y, z, w; };

__device__ __forceinline__ float bf2f(u16 u) {
  union { unsigned i; float f; } c; c.i = ((unsigned)u) << 16; return c.f;
}
__device__ __forceinline__ u16 f2bf(float f) {
  union { float f; unsigned i; } c; c.f = f;
  unsigned r = c.i + 0x7FFFu + ((c.i >> 16) & 1u);  // RNE
  return (u16)(r >> 16);
}

// ---------------------------------------------------------------- converts
__global__ __launch_bounds__(256) void cvt5_bf16_kernel(
    const float* __restrict__ i0, u16* __restrict__ o0, int n0,
    const float* __restrict__ i1, u16* __restrict__ o1, int n1,
    const float* __restrict__ i2, u16* __restrict__ o2, int n2,
    const float* __restrict__ i3, u16* __restrict__ o3, int n3,
    const float* __restrict__ i4, u16* __restrict__ o4, int n4) {
  const int stride = gridDim.x * blockDim.x;
  const int t0 = blockIdx.x * blockDim.x + threadIdx.x;
  const float* ins[5] = {i0, i1, i2, i3, i4};
  u16* outs[5] = {o0, o1, o2, o3, o4};
  const int ns[5] = {n0, n1, n2, n3, n4};
#pragma unroll
  for (int a = 0; a < 5; ++a) {
    const float* in = ins[a];
    u16* out = outs[a];
    for (int i = t0; i < ns[a]; i += stride) {
      float4 f = ((const float4*)in)[i];
      U4 u; u.x = f2bf(f.x); u.y = f2bf(f.y); u.z = f2bf(f.z); u.w = f2bf(f.w);
      ((U4*)out)[i] = u;
    }
  }
}

// ------------------------------------------------------------- segmentation
__global__ __launch_bounds__(64) void segment_kernel(
    const float* __restrict__ bnd, int* __restrict__ nchunks,
    int* __restrict__ starts, int* __restrict__ lens) {
  const int b = blockIdx.x;
  const int lane = threadIdx.x;
  int running = 0;
  for (int g = 0; g < SEQ / 64; ++g) {
    int s = g * 64 + lane;
    bool isb = bnd[b * SEQ + s] > THRESH;
    unsigned long long mask = __ballot(isb ? 1 : 0);
    int excl = __popcll(mask & ((1ULL << lane) - 1ULL));
    if (isb) {
      int c = running + excl;
      if (c <= MAXC) starts[b * (MAXC + 1) + c] = s;
    }
    running += __popcll(mask);
  }
  if (lane == 0) nchunks[b] = running;
  __syncthreads();
  int ncl = min(running, MAXC);
  for (int c = lane; c < MAXC; c += 64) {
    int v = 0;
    if (c < ncl) {
      int st = starts[b * (MAXC + 1) + c];
      int en = (c + 1 < running) ? starts[b * (MAXC + 1) + c + 1] : SEQ;
      v = en - st;
    }
    lens[b * MAXC + c] = v;
  }
}

// --------------------------------------------------- 256x256 pipelined GEMM
// Single phase per K-tile (BK=32): read 12 frags + stage t+3, lgkmcnt(0),
// 32-MFMA cluster, counted vmcnt(8), ONE barrier per tile. 4 LDS buffers
// (128KB), prefetch distance 3 (~1800cy > 900cy HBM latency).
// WAR: buf[(t+3)&3] == buf[(t-1)&3], dead since end-of-(t-1) barrier.
// Residency: per-wave vmcnt + barrier => block-wide t+1 resident.
__global__ __launch_bounds__(512, 2) void gemm256_kernel(
    const u16* __restrict__ A, const u16* __restrict__ B,
    const int M, const int N, const int K,
    const float* __restrict__ bias, u16* __restrict__ outB) {
  __shared__ __align__(16) u16 lds[4][2][8192];  // [buf][A/B][1024 slots * 8]
  const int tid = threadIdx.x;
  const int wid = tid >> 6;
  const int lane = tid & 63;
  const int cpx = gridDim.x >> 3;
  const int bid = ((int)blockIdx.x & 7) * cpx + ((int)blockIdx.x >> 3);
  const int NX = N >> 8;
  const int row0 = (bid / NX) << 8;
  const int col0 = (bid % NX) << 8;

  const int wr = wid >> 2;
  const int wc = wid & 3;
  const int rr = lane & 15;
  const int kg = lane >> 4;
  const int cw = rr * 4 + kg;
  const int slot = cw ^ ((cw >> 3) & 7);
  int srow[2], sk8[2];
#pragma unroll
  for (int i = 0; i < 2; ++i) {
    const int s = i * 512 + tid;
    const int g = s >> 6, c = s & 63;
    const int gch = c ^ ((c >> 3) & 7);
    srow[i] = g * 16 + (gch >> 2);
    sk8[i] = gch & 3;
  }

  const int NT = K >> 5;

#define STAGE(t)                                                              \
  {                                                                           \
    const int _b = (t) & 3;                                                   \
    const int _kb = (t) << 5;                                                 \
    _Pragma("unroll") for (int i = 0; i < 2; ++i) {                           \
      u16* ga = const_cast<u16*>(A) + (size_t)(row0 + srow[i]) * K + _kb +    \
                sk8[i] * 8;                                                   \
      u16* gb = const_cast<u16*>(B) + (size_t)(col0 + srow[i]) * K + _kb +    \
                sk8[i] * 8;                                                   \
      __builtin_amdgcn_global_load_lds(                                       \
          (__attribute__((address_space(1))) void*)ga,                        \
          (__attribute__((address_space(3))) void*)&lds[_b][0]                \
              [(i * 512 + wid * 64) * 8], 16, 0, 0);                          \
      __builtin_amdgcn_global_load_lds(                                       \
          (__attribute__((address_space(1))) void*)gb,                        \
          (__attribute__((address_space(3))) void*)&lds[_b][1]                \
              [(i * 512 + wid * 64) * 8], 16, 0, 0);                          \
    }                                                                         \
  }

  f32x4 acc[8][4] = {};

  // prologue: tiles 0..2 in flight (12 loads/wave); tile 0 resident
  STAGE(0); STAGE(1); STAGE(2);
  asm volatile("s_waitcnt vmcnt(8)" ::: "memory");
  __builtin_amdgcn_s_barrier();

  for (int t = 0; t < NT; ++t) {
    const int buf = t & 3;
    bf16x8 af[8], bf[4];
#pragma unroll
    for (int m = 0; m < 8; ++m)
      af[m] = *(const bf16x8*)&lds[buf][0][((wr * 8 + m) * 64 + slot) * 8];
#pragma unroll
    for (int n = 0; n < 4; ++n)
      bf[n] = *(const bf16x8*)&lds[buf][1][((wc * 4 + n) * 64 + slot) * 8];
    if (t + 3 < NT) STAGE(t + 3);
    asm volatile("s_waitcnt lgkmcnt(0)" ::: "memory");
    __builtin_amdgcn_sched_barrier(0);
    __builtin_amdgcn_s_setprio(1);
#pragma unroll
    for (int m = 0; m < 8; ++m)
#pragma unroll
      for (int n = 0; n < 4; ++n)
        acc[m][n] = __builtin_amdgcn_mfma_f32_16x16x32_bf16(af[m], bf[n], acc[m][n], 0, 0, 0);
    __builtin_amdgcn_s_setprio(0);
    // counted wait: ensure t+1 resident (oldest 4 loads), keep rest in flight
    if (t + 3 < NT) {
      asm volatile("s_waitcnt vmcnt(8)" ::: "memory");
    } else if (t + 2 < NT) {
      asm volatile("s_waitcnt vmcnt(4)" ::: "memory");
    } else if (t + 1 < NT) {
      asm volatile("s_waitcnt vmcnt(0)" ::: "memory");
    }
    __builtin_amdgcn_s_barrier();
  }
#undef STAGE

#pragma unroll
  for (int m = 0; m < 8; ++m) {
#pragma unroll
    for (int n = 0; n < 4; ++n) {
      const int col = col0 + wc * 64 + n * 16 + rr;
      const float bs = bias[col];
#pragma unroll
      for (int j = 0; j < 4; ++j) {
        const int row = row0 + wr * 128 + m * 16 + (lane >> 4) * 4 + j;
        outB[(size_t)row * N + col] = f2bf(acc[m][n][j] + bs);
      }
    }
  }
}

// -------------------------------------------------------------- 128^2 GEMM
// Double-buffered (prefetch 1): per tile {ds_read cur || stage next ->
// lgkmcnt(0) -> 16 MFMA -> vmcnt(0) (issued one tile early) -> barrier}.
// One barrier/tile; 32KB LDS keeps ~5 blocks/CU for TLP.
template <int MODE>
__global__ __launch_bounds__(256) void gemm_bf16_kernel(
    const u16* __restrict__ A, const u16* __restrict__ B,
    const int M, const int N, const int K,
    const float* __restrict__ bias,
    u16* __restrict__ outB, float* __restrict__ outF,
    const int* __restrict__ lens, const float* __restrict__ semb,
    const float* __restrict__ pos) {
  __shared__ __align__(16) u16 As[2][128 * 32];
  __shared__ __align__(16) u16 Bs[2][128 * 32];
  const int tid = threadIdx.x;
  const int wave = tid >> 6;
  const int lane = tid & 63;
  const int row0 = blockIdx.y * 128;
  const int col0 = blockIdx.x * 128;
  const int wm = (wave >> 1) * 64;
  const int wn = (wave & 1) * 64;
  const int gch = lane ^ ((lane >> 3) & 7);
  const int sr = gch >> 2;
  const int sc = (gch & 3) * 8;
  const int rr = lane & 15;
  const int kg = lane >> 4;
  const int cwant = rr * 4 + kg;
  const int slot = cwant ^ ((cwant >> 3) & 7);
  const int NT = K >> 5;
  f32x4 acc[4][4] = {};

#define STAGE128(t, bb)                                                       \
  {                                                                           \
    const int _k = (t) << 5;                                                  \
    _Pragma("unroll") for (int tt = 0; tt < 2; ++tt) {                        \
      const int li = wave * 2 + tt;                                           \
      u16* ga = const_cast<u16*>(A) + (size_t)(row0 + li * 16 + sr) * K +     \
                _k + sc;                                                      \
      u16* gb = const_cast<u16*>(B) + (size_t)(col0 + li * 16 + sr) * K +     \
                _k + sc;                                                      \
      __builtin_amdgcn_global_load_lds(                                       \
          (__attribute__((address_space(1))) void*)ga,                        \
          (__attribute__((address_space(3))) void*)(As[bb] + li * 512), 16,   \
          0, 0);                                                              \
      __builtin_amdgcn_global_load_lds(                                       \
          (__attribute__((address_space(1))) void*)gb,                        \
          (__attribute__((address_space(3))) void*)(Bs[bb] + li * 512), 16,   \
          0, 0);                                                              \
    }                                                                         \
  }

  STAGE128(0, 0);
  asm volatile("s_waitcnt vmcnt(0)" ::: "memory");
  __builtin_amdgcn_s_barrier();

  for (int t = 0; t < NT; ++t) {
    const int cb = t & 1;
    bf16x8 af[4], bfr[4];
#pragma unroll
    for (int m = 0; m < 4; ++m)
      af[m] = *(const bf16x8*)(As[cb] + ((wm >> 4) + m) * 512 + slot * 8);
#pragma unroll
    for (int n = 0; n < 4; ++n)
      bfr[n] = *(const bf16x8*)(Bs[cb] + ((wn >> 4) + n) * 512 + slot * 8);
    if (t + 1 < NT) STAGE128(t + 1, cb ^ 1);
    asm volatile("s_waitcnt lgkmcnt(0)" ::: "memory");
    __builtin_amdgcn_sched_barrier(0);
#pragma unroll
    for (int m = 0; m < 4; ++m)
#pragma unroll
      for (int n = 0; n < 4; ++n)
        acc[m][n] = __builtin_amdgcn_mfma_f32_16x16x32_bf16(af[m], bfr[n], acc[m][n], 0, 0, 0);
    if (t + 1 < NT) asm volatile("s_waitcnt vmcnt(0)" ::: "memory");
    __builtin_amdgcn_s_barrier();
  }
#undef STAGE128

  const int rg = (lane >> 4) * 4;
#pragma unroll
  for (int m = 0; m < 4; ++m) {
#pragma unroll
    for (int n = 0; n < 4; ++n) {
      const int col = col0 + wn + n * 16 + rr;
#pragma unroll
      for (int j = 0; j < 4; ++j) {
        const int row = row0 + wm + m * 16 + rg + j;
        float v = acc[m][n][j];
        if (MODE == 2) {
          const int len = lens[row];
          float val = 0.f;
          if (len > 0) {
            const int si = len < 1023 ? len : 1023;
            val = v + bias[col] + semb[(size_t)si * DM + col];
          }
          val += pos[(size_t)(row & (MAXC - 1)) * DM + col];
          outB[(size_t)row * N + col] = f2bf(val);
        } else if (MODE == 3) {
          float z = v + bias[col];
          float gel = 0.5f * z * (1.f + erff(z * 0.70710678118654752440f));
          outB[(size_t)row * N + col] = f2bf(gel);
        } else {
          outF[(size_t)row * N + col] = v + bias[col];
        }
      }
    }
  }
}

// ----------------------------------------------------- chunk attention v5
// One wave per (h,c,b). Register-only L<=16 fast path (93% of chunks).
// V-pooling vectorized: 2 keys/iter, U4 (8B) V loads, shfl_xor(32) combine.
__global__ __launch_bounds__(64) void chunk_attn_kernel(
    const u16* __restrict__ qkv, const int* __restrict__ nchunks,
    const int* __restrict__ starts, const int* __restrict__ lens,
    u16* __restrict__ pooled) {
  __shared__ float g_lds[SEQ];
  const int h = blockIdx.x;
  const int c = blockIdx.y;
  const int b = blockIdx.z;
  const int lane = threadIdx.x;
  const int nc = min(nchunks[b], MAXC);
  u16* prow = pooled + ((size_t)(b * MAXC + c)) * DM + h * DHEAD;
  if (c >= nc) {  // empty chunk: pooled ctx = 0
    U2 z; z.x = 0; z.y = 0;
    *(U2*)(prow + lane * 2) = z;
    return;
  }
  const int s0 = starts[b * (MAXC + 1) + c];
  const int L = lens[b * MAXC + c];
  const u16* Qb = qkv + ((size_t)(b * SEQ + s0)) * QKVN + h * DHEAD;
  const u16* Kb = Qb + DM;
  const u16* Vb = Qb + 2 * DM;

  const int col = lane & 15;
  const int grp = lane >> 4;
  const float scale = 0.08838834764831845f;  // 1/sqrt(128)
  const int half = lane >> 5;       // key parity this lane pools
  const int dl4 = (lane & 31) * 4;  // dim base (4 dims/lane over 32 lanes)

  float a[4] = {0.f, 0.f, 0.f, 0.f};

  if (L <= 16) {
    // ---------------- register-only single-tile path
    const int rc = col < L ? col : (L - 1);
    bf16x8 qf[4], kf[4];
#pragma unroll
    for (int s = 0; s < 4; ++s) {
      qf[s] = *(const bf16x8*)(Qb + (size_t)rc * QKVN + s * 32 + grp * 8);
      kf[s] = *(const bf16x8*)(Kb + (size_t)rc * QKVN + s * 32 + grp * 8);
    }
    f32x4 sc = {0.f, 0.f, 0.f, 0.f};
#pragma unroll
    for (int s = 0; s < 4; ++s)
      sc = __builtin_amdgcn_mfma_f32_16x16x32_bf16(qf[s], kf[s], sc, 0, 0, 0);
    const bool kvalid = col < L;
    float g = 0.f;
#pragma unroll
    for (int j = 0; j < 4; ++j) {
      float sj = sc[j] * scale;
      float mv = kvalid ? sj : -3e38f;
      mv = fmaxf(mv, __shfl_xor(mv, 1));
      mv = fmaxf(mv, __shfl_xor(mv, 2));
      mv = fmaxf(mv, __shfl_xor(mv, 4));
      mv = fmaxf(mv, __shfl_xor(mv, 8));
      float pv = kvalid ? __expf(sj - mv) : 0.f;
      float dv = pv;
      dv += __shfl_xor(dv, 1);
      dv += __shfl_xor(dv, 2);
      dv += __shfl_xor(dv, 4);
      dv += __shfl_xor(dv, 8);
      const bool rv = (grp * 4 + j) < L;
      g += rv ? pv / dv : 0.f;
    }
    g += __shfl_xor(g, 16);
    g += __shfl_xor(g, 32);   // lanes 0-15 (replicated): column sums
    for (int j = 0; j < L; j += 2) {
      const int jj = j + half;
      const bool jv = jj < L;
      float gj = __shfl(g, jv ? jj : 0);
      if (!jv) gj = 0.f;
      const int jc = jv ? jj : 0;
      U4 vv = *(const U4*)(Vb + (size_t)jc * QKVN + dl4);
      a[0] += gj * bf2f(vv.x); a[1] += gj * bf2f(vv.y);
      a[2] += gj * bf2f(vv.z); a[3] += gj * bf2f(vv.w);
    }
  } else {
    // ---------------- general tiled path (wave-local LDS g, no barriers)
    float* gw = g_lds;
    for (int j = lane; j < L; j += 64) gw[j] = 0.f;
    const int NT = (L + 15) >> 4;
    for (int qt = 0; qt < NT; ++qt) {
      const int qr = qt * 16 + col;
      const int qrc = qr < L ? qr : (L - 1);
      bf16x8 qf[4];
#pragma unroll
      for (int s = 0; s < 4; ++s)
        qf[s] = *(const bf16x8*)(Qb + (size_t)qrc * QKVN + s * 32 + grp * 8);

      float m[4] = {-3e38f, -3e38f, -3e38f, -3e38f};
      float den[4] = {0.f, 0.f, 0.f, 0.f};
      for (int kt = 0; kt < NT; ++kt) {
        const int kr = kt * 16 + col;
        const bool kvalid = kr < L;
        const int krc = kvalid ? kr : (L - 1);
        f32x4 sc = {0.f, 0.f, 0.f, 0.f};
#pragma unroll
        for (int s = 0; s < 4; ++s) {
          bf16x8 kf = *(const bf16x8*)(Kb + (size_t)krc * QKVN + s * 32 + grp * 8);
          sc = __builtin_amdgcn_mfma_f32_16x16x32_bf16(qf[s], kf, sc, 0, 0, 0);
        }
#pragma unroll
        for (int j = 0; j < 4; ++j) {
          float sj = sc[j] * scale;
          float mv = kvalid ? sj : -3e38f;
          mv = fmaxf(mv, __shfl_xor(mv, 1));
          mv = fmaxf(mv, __shfl_xor(mv, 2));
          mv = fmaxf(mv, __shfl_xor(mv, 4));
          mv = fmaxf(mv, __shfl_xor(mv, 8));
          float mn = fmaxf(m[j], mv);
          float pv = kvalid ? __expf(sj - mn) : 0.f;
          pv += __shfl_xor(pv, 1);
          pv += __shfl_xor(pv, 2);
          pv += __shfl_xor(pv, 4);
          pv += __shfl_xor(pv, 8);
          den[j] = den[j] * __expf(m[j] - mn) + pv;
          m[j] = mn;
        }
      }
      float inv[4];
#pragma unroll
      for (int j = 0; j < 4; ++j) {
        const bool rv = (qt * 16 + grp * 4 + j) < L;
        inv[j] = rv ? 1.f / den[j] : 0.f;
      }
      for (int kt = 0; kt < NT; ++kt) {
        const int kr = kt * 16 + col;
        const bool kvalid = kr < L;
        const int krc = kvalid ? kr : (L - 1);
        f32x4 sc = {0.f, 0.f, 0.f, 0.f};
#pragma unroll
        for (int s = 0; s < 4; ++s) {
          bf16x8 kf = *(const bf16x8*)(Kb + (size_t)krc * QKVN + s * 32 + grp * 8);
          sc = __builtin_amdgcn_mfma_f32_16x16x32_bf16(qf[s], kf, sc, 0, 0, 0);
        }
        float colsum = 0.f;
#pragma unroll
        for (int j = 0; j < 4; ++j)
          colsum += __expf(sc[j] * scale - m[j]) * inv[j];
        colsum += __shfl_xor(colsum, 16);
        colsum += __shfl_xor(colsum, 32);
        if (grp == 0 && kvalid) gw[kt * 16 + col] += colsum;
      }
    }
    for (int j = 0; j < L; j += 2) {
      const int jj = j + half;
      const bool jv = jj < L;
      float gj = jv ? gw[jj] : 0.f;
      const int jc = jv ? jj : 0;
      U4 vv = *(const U4*)(Vb + (size_t)jc * QKVN + dl4);
      a[0] += gj * bf2f(vv.x); a[1] += gj * bf2f(vv.y);
      a[2] += gj * bf2f(vv.z); a[3] += gj * bf2f(vv.w);
    }
  }
  const float invL = 1.f / (float)L;
#pragma unroll
  for (int i = 0; i < 4; ++i) {
    a[i] += __shfl_xor(a[i], 32);
    a[i] *= invL;
  }
  if (lane < 32) {
    U4 r; r.x = f2bf(a[0]); r.y = f2bf(a[1]); r.z = f2bf(a[2]); r.w = f2bf(a[3]);
    *(U4*)(prow + dl4) = r;
  }
}

// ---------------------------------------------------------------- LayerNorm
__global__ __launch_bounds__(256) void ln_kernel(
    const float* __restrict__ h2, const float* __restrict__ gamma,
    const float* __restrict__ beta, float* __restrict__ out) {
  const int row = blockIdx.x;
  const float* x = h2 + (size_t)row * DM;
  float* o = out + (size_t)row * DM;
  const int tid = threadIdx.x;
  float v[6];
  float s = 0.f;
#pragma unroll
  for (int i = 0; i < 6; ++i) { v[i] = x[tid + i * 256]; s += v[i]; }
  __shared__ float red[8];
#pragma unroll
  for (int off = 32; off; off >>= 1) s += __shfl_xor(s, off);
  if ((tid & 63) == 0) red[tid >> 6] = s;
  __syncthreads();
  const float mu = (red[0] + red[1] + red[2] + red[3]) * (1.f / (float)DM);
  float vs = 0.f;
#pragma unroll
  for (int i = 0; i < 6; ++i) { float d = v[i] - mu; vs += d * d; }
#pragma unroll
  for (int off = 32; off; off >>= 1) vs += __shfl_xor(vs, off);
  __shared__ float red2[8];
  if ((tid & 63) == 0) red2[tid >> 6] = vs;
  __syncthreads();
  const float var = (red2[0] + red2[1] + red2[2] + red2[3]) * (1.f / (float)DM);
  const float inv = rsqrtf(var + 1e-5f);
#pragma unroll
  for (int i = 0; i < 6; ++i) {
    const int cidx = tid + i * 256;
    o[cidx] = (v[i] - mu) * inv * gamma[cidx] + beta[cidx];
  }
}

// ------------------------------------------------------------------ launch
extern "C" void kernel_launch(void* const* d_in, const int* in_sizes, int n_in,
                              void* d_out, int out_size, void* d_ws, size_t ws_size,
                              hipStream_t stream) {
  const float* x    = (const float*)d_in[0];
  const float* bnd  = (const float*)d_in[1];
  const float* wqkv = (const float*)d_in[2];
  const float* bqkv = (const float*)d_in[3];
  const float* wout = (const float*)d_in[4];
  const float* bout = (const float*)d_in[5];
  const float* w1   = (const float*)d_in[6];
  const float* b1   = (const float*)d_in[7];
  const float* w2   = (const float*)d_in[8];
  const float* b2   = (const float*)d_in[9];
  const float* lng  = (const float*)d_in[10];
  const float* lnb  = (const float*)d_in[11];
  const float* pos  = (const float*)d_in[12];
  const float* semb = (const float*)d_in[13];
  float* out = (float*)d_out;

  char* ws = (char*)d_ws;
  size_t off = 0;
  auto alloc = [&](size_t bytes) -> char* {
    char* p = ws + off;
    off += (bytes + 255) & ~(size_t)255;
    return p;
  };
  u16* x_bf    = (u16*)alloc((size_t)NB * SEQ * DM * 2);
  u16* wqkv_bf = (u16*)alloc((size_t)3 * DM * DM * 2);
  u16* wout_bf = (u16*)alloc((size_t)DM * DM * 2);
  u16* w1_bf   = (u16*)alloc((size_t)2 * DM * DM * 2);
  u16* w2_bf   = (u16*)alloc((size_t)2 * DM * DM * 2);
  u16* qkv_bf  = (u16*)alloc((size_t)NB * SEQ * QKVN * 2);
  int* nchunks = (int*)alloc(NB * 4);
  int* starts  = (int*)alloc(NB * (MAXC + 1) * 4);
  int* lens    = (int*)alloc(NB * MAXC * 4);
  u16* pooled  = (u16*)alloc((size_t)NB * MAXC * DM * 2);
  u16* chunks  = (u16*)alloc((size_t)NB * MAXC * DM * 2);
  u16* h1      = (u16*)alloc((size_t)NB * MAXC * 2 * DM * 2);
  float* h2    = (float*)alloc((size_t)NB * MAXC * DM * 4);
  (void)ws_size; (void)in_sizes; (void)n_in; (void)out_size;

  cvt5_bf16_kernel<<<2048, 256, 0, stream>>>(
      x, x_bf, NB * SEQ * DM / 4,
      wqkv, wqkv_bf, 3 * DM * DM / 4,
      wout, wout_bf, DM * DM / 4,
      w1, w1_bf, 2 * DM * DM / 4,
      w2, w2_bf, 2 * DM * DM / 4);

  segment_kernel<<<NB, 64, 0, stream>>>(bnd, nchunks, starts, lens);

  gemm256_kernel<<<(NB * SEQ / 256) * (QKVN / 256), 512, 0, stream>>>(
      x_bf, wqkv_bf, NB * SEQ, QKVN, DM, bqkv, qkv_bf);

  chunk_attn_kernel<<<dim3(NHEAD, MAXC, NB), 64, 0, stream>>>(
      qkv_bf, nchunks, starts, lens, pooled);

  gemm_bf16_kernel<2><<<dim3(DM / 128, NB * MAXC / 128), 256, 0, stream>>>(
      pooled, wout_bf, NB * MAXC, DM, DM, bout, chunks, nullptr, lens, semb, pos);

  gemm_bf16_kernel<3><<<dim3(2 * DM / 128, NB * MAXC / 128), 256, 0, stream>>>(
      chunks, w1_bf, NB * MAXC, 2 * DM, DM, b1, h1, nullptr, nullptr, nullptr, nullptr);

  gemm_bf16_kernel<4><<<dim3(DM / 128, NB * MAXC / 128), 256, 0, stream>>>(
      h1, w2_bf, NB * MAXC, DM, 2 * DM, b2, nullptr, h2, nullptr, nullptr, nullptr);

  ln_kernel<<<NB * MAXC, 256, 0, stream>>>(h2, lng, lnb, out);
}

// Round 9
// 352.452 us; speedup vs baseline: 1.1842x; 1.0028x over previous
//
#include <hip/hip_runtime.h>
#include <math.h>

// Problem constants
#define NB 8
#define SEQ 1024
#define DM 1536
#define NHEAD 12
#define DHEAD 128
#define MAXC 256
#define QKVN 4608
#define THRESH 0.85f

typedef unsigned short u16;
typedef __attribute__((ext_vector_type(8))) __bf16 bf16x8;
typedef __attribute__((ext_vector_type(4))) float f32x4;

struct __align__(4) U2 { u16 x, y; };
struct __align__(8) U4 { u16 x, y, z, w; };

__device__ __forceinline__ float bf2f(u16 u) {
  union { unsigned i; float f; } c; c.i = ((unsigned)u) << 16; return c.f;
}
__device__ __forceinline__ u16 f2bf(float f) {
  union { float f; unsigned i; } c; c.f = f;
  unsigned r = c.i + 0x7FFFu + ((c.i >> 16) & 1u);  // RNE
  return (u16)(r >> 16);
}

// ---------------------------------------------------------------- converts
__global__ __launch_bounds__(256) void cvt5_bf16_kernel(
    const float* __restrict__ i0, u16* __restrict__ o0, int n0,
    const float* __restrict__ i1, u16* __restrict__ o1, int n1,
    const float* __restrict__ i2, u16* __restrict__ o2, int n2,
    const float* __restrict__ i3, u16* __restrict__ o3, int n3,
    const float* __restrict__ i4, u16* __restrict__ o4, int n4) {
  const int stride = gridDim.x * blockDim.x;
  const int t0 = blockIdx.x * blockDim.x + threadIdx.x;
  const float* ins[5] = {i0, i1, i2, i3, i4};
  u16* outs[5] = {o0, o1, o2, o3, o4};
  const int ns[5] = {n0, n1, n2, n3, n4};
#pragma unroll
  for (int a = 0; a < 5; ++a) {
    const float* in = ins[a];
    u16* out = outs[a];
    for (int i = t0; i < ns[a]; i += stride) {
      float4 f = ((const float4*)in)[i];
      U4 u; u.x = f2bf(f.x); u.y = f2bf(f.y); u.z = f2bf(f.z); u.w = f2bf(f.w);
      ((U4*)out)[i] = u;
    }
  }
}

// ------------------------------------------------------------- segmentation
__global__ __launch_bounds__(64) void segment_kernel(
    const float* __restrict__ bnd, int* __restrict__ nchunks,
    int* __restrict__ starts, int* __restrict__ lens) {
  const int b = blockIdx.x;
  const int lane = threadIdx.x;
  int running = 0;
  for (int g = 0; g < SEQ / 64; ++g) {
    int s = g * 64 + lane;
    bool isb = bnd[b * SEQ + s] > THRESH;
    unsigned long long mask = __ballot(isb ? 1 : 0);
    int excl = __popcll(mask & ((1ULL << lane) - 1ULL));
    if (isb) {
      int c = running + excl;
      if (c <= MAXC) starts[b * (MAXC + 1) + c] = s;
    }
    running += __popcll(mask);
  }
  if (lane == 0) nchunks[b] = running;
  __syncthreads();
  int ncl = min(running, MAXC);
  for (int c = lane; c < MAXC; c += 64) {
    int v = 0;
    if (c < ncl) {
      int st = starts[b * (MAXC + 1) + c];
      int en = (c + 1 < running) ? starts[b * (MAXC + 1) + c + 1] : SEQ;
      v = en - st;
    }
    lens[b * MAXC + c] = v;
  }
}

// --------------------------------------------------- 256x256 pipelined GEMM
// BK=32, 4 LDS buffers, prefetch distance 3, counted vmcnt(8), one barrier
// per tile. NO forced lgkmcnt(0)/sched_barrier before the MFMA cluster:
// ds_reads issued in consumption order (B frags then A in m-order); the
// compiler's counted lgkmcnt lets quadrant-0 MFMAs start after 5 loads while
// the remaining reads return under MFMA (m97/m141 lesson: don't pin order).
__global__ __launch_bounds__(512, 2) void gemm256_kernel(
    const u16* __restrict__ A, const u16* __restrict__ B,
    const int M, const int N, const int K,
    const float* __restrict__ bias, u16* __restrict__ outB) {
  __shared__ __align__(16) u16 lds[4][2][8192];  // [buf][A/B][1024 slots * 8]
  const int tid = threadIdx.x;
  const int wid = tid >> 6;
  const int lane = tid & 63;
  const int cpx = gridDim.x >> 3;
  const int bid = ((int)blockIdx.x & 7) * cpx + ((int)blockIdx.x >> 3);
  const int NX = N >> 8;
  const int row0 = (bid / NX) << 8;
  const int col0 = (bid % NX) << 8;

  const int wr = wid >> 2;
  const int wc = wid & 3;
  const int rr = lane & 15;
  const int kg = lane >> 4;
  const int cw = rr * 4 + kg;
  const int slot = cw ^ ((cw >> 3) & 7);
  int srow[2], sk8[2];
#pragma unroll
  for (int i = 0; i < 2; ++i) {
    const int s = i * 512 + tid;
    const int g = s >> 6, c = s & 63;
    const int gch = c ^ ((c >> 3) & 7);
    srow[i] = g * 16 + (gch >> 2);
    sk8[i] = gch & 3;
  }

  const int NT = K >> 5;

#define STAGE(t)                                                              \
  {                                                                           \
    const int _b = (t) & 3;                                                   \
    const int _kb = (t) << 5;                                                 \
    _Pragma("unroll") for (int i = 0; i < 2; ++i) {                           \
      u16* ga = const_cast<u16*>(A) + (size_t)(row0 + srow[i]) * K + _kb +    \
                sk8[i] * 8;                                                   \
      u16* gb = const_cast<u16*>(B) + (size_t)(col0 + srow[i]) * K + _kb +    \
                sk8[i] * 8;                                                   \
      __builtin_amdgcn_global_load_lds(                                       \
          (__attribute__((address_space(1))) void*)ga,                        \
          (__attribute__((address_space(3))) void*)&lds[_b][0]                \
              [(i * 512 + wid * 64) * 8], 16, 0, 0);                          \
      __builtin_amdgcn_global_load_lds(                                       \
          (__attribute__((address_space(1))) void*)gb,                        \
          (__attribute__((address_space(3))) void*)&lds[_b][1]                \
              [(i * 512 + wid * 64) * 8], 16, 0, 0);                          \
    }                                                                         \
  }

  f32x4 acc[8][4] = {};

  // prologue: tiles 0..2 in flight (12 loads/wave); tile 0 resident
  STAGE(0); STAGE(1); STAGE(2);
  asm volatile("s_waitcnt vmcnt(8)" ::: "memory");
  __builtin_amdgcn_s_barrier();

  for (int t = 0; t < NT; ++t) {
    const int buf = t & 3;
    // consumption-ordered reads: all B first, then A in m-order
    bf16x8 bf[4], af[8];
#pragma unroll
    for (int n = 0; n < 4; ++n)
      bf[n] = *(const bf16x8*)&lds[buf][1][((wc * 4 + n) * 64 + slot) * 8];
#pragma unroll
    for (int m = 0; m < 8; ++m)
      af[m] = *(const bf16x8*)&lds[buf][0][((wr * 8 + m) * 64 + slot) * 8];
    if (t + 3 < NT) STAGE(t + 3);
    __builtin_amdgcn_s_setprio(1);
#pragma unroll
    for (int m = 0; m < 8; ++m)
#pragma unroll
      for (int n = 0; n < 4; ++n)
        acc[m][n] = __builtin_amdgcn_mfma_f32_16x16x32_bf16(af[m], bf[n], acc[m][n], 0, 0, 0);
    __builtin_amdgcn_s_setprio(0);
    // counted wait: ensure t+1 resident (oldest 4 loads), keep rest in flight
    if (t + 3 < NT) {
      asm volatile("s_waitcnt vmcnt(8)" ::: "memory");
    } else if (t + 2 < NT) {
      asm volatile("s_waitcnt vmcnt(4)" ::: "memory");
    } else if (t + 1 < NT) {
      asm volatile("s_waitcnt vmcnt(0)" ::: "memory");
    }
    __builtin_amdgcn_s_barrier();
  }
#undef STAGE

#pragma unroll
  for (int m = 0; m < 8; ++m) {
#pragma unroll
    for (int n = 0; n < 4; ++n) {
      const int col = col0 + wc * 64 + n * 16 + rr;
      const float bs = bias[col];
#pragma unroll
      for (int j = 0; j < 4; ++j) {
        const int row = row0 + wr * 128 + m * 16 + (lane >> 4) * 4 + j;
        outB[(size_t)row * N + col] = f2bf(acc[m][n][j] + bs);
      }
    }
  }
}

// -------------------------------------------------------------- 128^2 GEMM
// Double-buffered; consumption-ordered reads; no forced lgkmcnt pin.
template <int MODE>
__global__ __launch_bounds__(256) void gemm_bf16_kernel(
    const u16* __restrict__ A, const u16* __restrict__ B,
    const int M, const int N, const int K,
    const float* __restrict__ bias,
    u16* __restrict__ outB, float* __restrict__ outF,
    const int* __restrict__ lens, const float* __restrict__ semb,
    const float* __restrict__ pos) {
  __shared__ __align__(16) u16 As[2][128 * 32];
  __shared__ __align__(16) u16 Bs[2][128 * 32];
  const int tid = threadIdx.x;
  const int wave = tid >> 6;
  const int lane = tid & 63;
  const int row0 = blockIdx.y * 128;
  const int col0 = blockIdx.x * 128;
  const int wm = (wave >> 1) * 64;
  const int wn = (wave & 1) * 64;
  const int gch = lane ^ ((lane >> 3) & 7);
  const int sr = gch >> 2;
  const int sc = (gch & 3) * 8;
  const int rr = lane & 15;
  const int kg = lane >> 4;
  const int cwant = rr * 4 + kg;
  const int slot = cwant ^ ((cwant >> 3) & 7);
  const int NT = K >> 5;
  f32x4 acc[4][4] = {};

#define STAGE128(t, bb)                                                       \
  {                                                                           \
    const int _k = (t) << 5;                                                  \
    _Pragma("unroll") for (int tt = 0; tt < 2; ++tt) {                        \
      const int li = wave * 2 + tt;                                           \
      u16* ga = const_cast<u16*>(A) + (size_t)(row0 + li * 16 + sr) * K +     \
                _k + sc;                                                      \
      u16* gb = const_cast<u16*>(B) + (size_t)(col0 + li * 16 + sr) * K +     \
                _k + sc;                                                      \
      __builtin_amdgcn_global_load_lds(                                       \
          (__attribute__((address_space(1))) void*)ga,                        \
          (__attribute__((address_space(3))) void*)(As[bb] + li * 512), 16,   \
          0, 0);                                                              \
      __builtin_amdgcn_global_load_lds(                                       \
          (__attribute__((address_space(1))) void*)gb,                        \
          (__attribute__((address_space(3))) void*)(Bs[bb] + li * 512), 16,   \
          0, 0);                                                              \
    }                                                                         \
  }

  STAGE128(0, 0);
  asm volatile("s_waitcnt vmcnt(0)" ::: "memory");
  __builtin_amdgcn_s_barrier();

  for (int t = 0; t < NT; ++t) {
    const int cb = t & 1;
    bf16x8 bfr[4], af[4];
#pragma unroll
    for (int n = 0; n < 4; ++n)
      bfr[n] = *(const bf16x8*)(Bs[cb] + ((wn >> 4) + n) * 512 + slot * 8);
#pragma unroll
    for (int m = 0; m < 4; ++m)
      af[m] = *(const bf16x8*)(As[cb] + ((wm >> 4) + m) * 512 + slot * 8);
    if (t + 1 < NT) STAGE128(t + 1, cb ^ 1);
#pragma unroll
    for (int m = 0; m < 4; ++m)
#pragma unroll
      for (int n = 0; n < 4; ++n)
        acc[m][n] = __builtin_amdgcn_mfma_f32_16x16x32_bf16(af[m], bfr[n], acc[m][n], 0, 0, 0);
    if (t + 1 < NT) asm volatile("s_waitcnt vmcnt(0)" ::: "memory");
    __builtin_amdgcn_s_barrier();
  }
#undef STAGE128

  const int rg = (lane >> 4) * 4;
#pragma unroll
  for (int m = 0; m < 4; ++m) {
#pragma unroll
    for (int n = 0; n < 4; ++n) {
      const int col = col0 + wn + n * 16 + rr;
#pragma unroll
      for (int j = 0; j < 4; ++j) {
        const int row = row0 + wm + m * 16 + rg + j;
        float v = acc[m][n][j];
        if (MODE == 2) {
          const int len = lens[row];
          float val = 0.f;
          if (len > 0) {
            const int si = len < 1023 ? len : 1023;
            val = v + bias[col] + semb[(size_t)si * DM + col];
          }
          val += pos[(size_t)(row & (MAXC - 1)) * DM + col];
          outB[(size_t)row * N + col] = f2bf(val);
        } else if (MODE == 3) {
          float z = v + bias[col];
          float gel = 0.5f * z * (1.f + erff(z * 0.70710678118654752440f));
          outB[(size_t)row * N + col] = f2bf(gel);
        } else {
          outF[(size_t)row * N + col] = v + bias[col];
        }
      }
    }
  }
}

// ----------------------------------------------------- chunk attention v5
// One wave per (h,c,b). Register-only L<=16 fast path (93% of chunks).
// V-pooling vectorized: 2 keys/iter, U4 (8B) V loads, shfl_xor(32) combine.
__global__ __launch_bounds__(64) void chunk_attn_kernel(
    const u16* __restrict__ qkv, const int* __restrict__ nchunks,
    const int* __restrict__ starts, const int* __restrict__ lens,
    u16* __restrict__ pooled) {
  __shared__ float g_lds[SEQ];
  const int h = blockIdx.x;
  const int c = blockIdx.y;
  const int b = blockIdx.z;
  const int lane = threadIdx.x;
  const int nc = min(nchunks[b], MAXC);
  u16* prow = pooled + ((size_t)(b * MAXC + c)) * DM + h * DHEAD;
  if (c >= nc) {  // empty chunk: pooled ctx = 0
    U2 z; z.x = 0; z.y = 0;
    *(U2*)(prow + lane * 2) = z;
    return;
  }
  const int s0 = starts[b * (MAXC + 1) + c];
  const int L = lens[b * MAXC + c];
  const u16* Qb = qkv + ((size_t)(b * SEQ + s0)) * QKVN + h * DHEAD;
  const u16* Kb = Qb + DM;
  const u16* Vb = Qb + 2 * DM;

  const int col = lane & 15;
  const int grp = lane >> 4;
  const float scale = 0.08838834764831845f;  // 1/sqrt(128)
  const int half = lane >> 5;       // key parity this lane pools
  const int dl4 = (lane & 31) * 4;  // dim base (4 dims/lane over 32 lanes)

  float a[4] = {0.f, 0.f, 0.f, 0.f};

  if (L <= 16) {
    // ---------------- register-only single-tile path
    const int rc = col < L ? col : (L - 1);
    bf16x8 qf[4], kf[4];
#pragma unroll
    for (int s = 0; s < 4; ++s) {
      qf[s] = *(const bf16x8*)(Qb + (size_t)rc * QKVN + s * 32 + grp * 8);
      kf[s] = *(const bf16x8*)(Kb + (size_t)rc * QKVN + s * 32 + grp * 8);
    }
    f32x4 sc = {0.f, 0.f, 0.f, 0.f};
#pragma unroll
    for (int s = 0; s < 4; ++s)
      sc = __builtin_amdgcn_mfma_f32_16x16x32_bf16(qf[s], kf[s], sc, 0, 0, 0);
    const bool kvalid = col < L;
    float g = 0.f;
#pragma unroll
    for (int j = 0; j < 4; ++j) {
      float sj = sc[j] * scale;
      float mv = kvalid ? sj : -3e38f;
      mv = fmaxf(mv, __shfl_xor(mv, 1));
      mv = fmaxf(mv, __shfl_xor(mv, 2));
      mv = fmaxf(mv, __shfl_xor(mv, 4));
      mv = fmaxf(mv, __shfl_xor(mv, 8));
      float pv = kvalid ? __expf(sj - mv) : 0.f;
      float dv = pv;
      dv += __shfl_xor(dv, 1);
      dv += __shfl_xor(dv, 2);
      dv += __shfl_xor(dv, 4);
      dv += __shfl_xor(dv, 8);
      const bool rv = (grp * 4 + j) < L;
      g += rv ? pv / dv : 0.f;
    }
    g += __shfl_xor(g, 16);
    g += __shfl_xor(g, 32);   // lanes 0-15 (replicated): column sums
    for (int j = 0; j < L; j += 2) {
      const int jj = j + half;
      const bool jv = jj < L;
      float gj = __shfl(g, jv ? jj : 0);
      if (!jv) gj = 0.f;
      const int jc = jv ? jj : 0;
      U4 vv = *(const U4*)(Vb + (size_t)jc * QKVN + dl4);
      a[0] += gj * bf2f(vv.x); a[1] += gj * bf2f(vv.y);
      a[2] += gj * bf2f(vv.z); a[3] += gj * bf2f(vv.w);
    }
  } else {
    // ---------------- general tiled path (wave-local LDS g, no barriers)
    float* gw = g_lds;
    for (int j = lane; j < L; j += 64) gw[j] = 0.f;
    const int NT = (L + 15) >> 4;
    for (int qt = 0; qt < NT; ++qt) {
      const int qr = qt * 16 + col;
      const int qrc = qr < L ? qr : (L - 1);
      bf16x8 qf[4];
#pragma unroll
      for (int s = 0; s < 4; ++s)
        qf[s] = *(const bf16x8*)(Qb + (size_t)qrc * QKVN + s * 32 + grp * 8);

      float m[4] = {-3e38f, -3e38f, -3e38f, -3e38f};
      float den[4] = {0.f, 0.f, 0.f, 0.f};
      for (int kt = 0; kt < NT; ++kt) {
        const int kr = kt * 16 + col;
        const bool kvalid = kr < L;
        const int krc = kvalid ? kr : (L - 1);
        f32x4 sc = {0.f, 0.f, 0.f, 0.f};
#pragma unroll
        for (int s = 0; s < 4; ++s) {
          bf16x8 kf = *(const bf16x8*)(Kb + (size_t)krc * QKVN + s * 32 + grp * 8);
          sc = __builtin_amdgcn_mfma_f32_16x16x32_bf16(qf[s], kf, sc, 0, 0, 0);
        }
#pragma unroll
        for (int j = 0; j < 4; ++j) {
          float sj = sc[j] * scale;
          float mv = kvalid ? sj : -3e38f;
          mv = fmaxf(mv, __shfl_xor(mv, 1));
          mv = fmaxf(mv, __shfl_xor(mv, 2));
          mv = fmaxf(mv, __shfl_xor(mv, 4));
          mv = fmaxf(mv, __shfl_xor(mv, 8));
          float mn = fmaxf(m[j], mv);
          float pv = kvalid ? __expf(sj - mn) : 0.f;
          pv += __shfl_xor(pv, 1);
          pv += __shfl_xor(pv, 2);
          pv += __shfl_xor(pv, 4);
          pv += __shfl_xor(pv, 8);
          den[j] = den[j] * __expf(m[j] - mn) + pv;
          m[j] = mn;
        }
      }
      float inv[4];
#pragma unroll
      for (int j = 0; j < 4; ++j) {
        const bool rv = (qt * 16 + grp * 4 + j) < L;
        inv[j] = rv ? 1.f / den[j] : 0.f;
      }
      for (int kt = 0; kt < NT; ++kt) {
        const int kr = kt * 16 + col;
        const bool kvalid = kr < L;
        const int krc = kvalid ? kr : (L - 1);
        f32x4 sc = {0.f, 0.f, 0.f, 0.f};
#pragma unroll
        for (int s = 0; s < 4; ++s) {
          bf16x8 kf = *(const bf16x8*)(Kb + (size_t)krc * QKVN + s * 32 + grp * 8);
          sc = __builtin_amdgcn_mfma_f32_16x16x32_bf16(qf[s], kf, sc, 0, 0, 0);
        }
        float colsum = 0.f;
#pragma unroll
        for (int j = 0; j < 4; ++j)
          colsum += __expf(sc[j] * scale - m[j]) * inv[j];
        colsum += __shfl_xor(colsum, 16);
        colsum += __shfl_xor(colsum, 32);
        if (grp == 0 && kvalid) gw[kt * 16 + col] += colsum;
      }
    }
    for (int j = 0; j < L; j += 2) {
      const int jj = j + half;
      const bool jv = jj < L;
      float gj = jv ? gw[jj] : 0.f;
      const int jc = jv ? jj : 0;
      U4 vv = *(const U4*)(Vb + (size_t)jc * QKVN + dl4);
      a[0] += gj * bf2f(vv.x); a[1] += gj * bf2f(vv.y);
      a[2] += gj * bf2f(vv.z); a[3] += gj * bf2f(vv.w);
    }
  }
  const float invL = 1.f / (float)L;
#pragma unroll
  for (int i = 0; i < 4; ++i) {
    a[i] += __shfl_xor(a[i], 32);
    a[i] *= invL;
  }
  if (lane < 32) {
    U4 r; r.x = f2bf(a[0]); r.y = f2bf(a[1]); r.z = f2bf(a[2]); r.w = f2bf(a[3]);
    *(U4*)(prow + dl4) = r;
  }
}

// ---------------------------------------------------------------- LayerNorm
__global__ __launch_bounds__(256) void ln_kernel(
    const float* __restrict__ h2, const float* __restrict__ gamma,
    const float* __restrict__ beta, float* __restrict__ out) {
  const int row = blockIdx.x;
  const float* x = h2 + (size_t)row * DM;
  float* o = out + (size_t)row * DM;
  const int tid = threadIdx.x;
  float v[6];
  float s = 0.f;
#pragma unroll
  for (int i = 0; i < 6; ++i) { v[i] = x[tid + i * 256]; s += v[i]; }
  __shared__ float red[8];
#pragma unroll
  for (int off = 32; off; off >>= 1) s += __shfl_xor(s, off);
  if ((tid & 63) == 0) red[tid >> 6] = s;
  __syncthreads();
  const float mu = (red[0] + red[1] + red[2] + red[3]) * (1.f / (float)DM);
  float vs = 0.f;
#pragma unroll
  for (int i = 0; i < 6; ++i) { float d = v[i] - mu; vs += d * d; }
#pragma unroll
  for (int off = 32; off; off >>= 1) vs += __shfl_xor(vs, off);
  __shared__ float red2[8];
  if ((tid & 63) == 0) red2[tid >> 6] = vs;
  __syncthreads();
  const float var = (red2[0] + red2[1] + red2[2] + red2[3]) * (1.f / (float)DM);
  const float inv = rsqrtf(var + 1e-5f);
#pragma unroll
  for (int i = 0; i < 6; ++i) {
    const int cidx = tid + i * 256;
    o[cidx] = (v[i] - mu) * inv * gamma[cidx] + beta[cidx];
  }
}

// ------------------------------------------------------------------ launch
extern "C" void kernel_launch(void* const* d_in, const int* in_sizes, int n_in,
                              void* d_out, int out_size, void* d_ws, size_t ws_size,
                              hipStream_t stream) {
  const float* x    = (const float*)d_in[0];
  const float* bnd  = (const float*)d_in[1];
  const float* wqkv = (const float*)d_in[2];
  const float* bqkv = (const float*)d_in[3];
  const float* wout = (const float*)d_in[4];
  const float* bout = (const float*)d_in[5];
  const float* w1   = (const float*)d_in[6];
  const float* b1   = (const float*)d_in[7];
  const float* w2   = (const float*)d_in[8];
  const float* b2   = (const float*)d_in[9];
  const float* lng  = (const float*)d_in[10];
  const float* lnb  = (const float*)d_in[11];
  const float* pos  = (const float*)d_in[12];
  const float* semb = (const float*)d_in[13];
  float* out = (float*)d_out;

  char* ws = (char*)d_ws;
  size_t off = 0;
  auto alloc = [&](size_t bytes) -> char* {
    char* p = ws + off;
    off += (bytes + 255) & ~(size_t)255;
    return p;
  };
  u16* x_bf    = (u16*)alloc((size_t)NB * SEQ * DM * 2);
  u16* wqkv_bf = (u16*)alloc((size_t)3 * DM * DM * 2);
  u16* wout_bf = (u16*)alloc((size_t)DM * DM * 2);
  u16* w1_bf   = (u16*)alloc((size_t)2 * DM * DM * 2);
  u16* w2_bf   = (u16*)alloc((size_t)2 * DM * DM * 2);
  u16* qkv_bf  = (u16*)alloc((size_t)NB * SEQ * QKVN * 2);
  int* nchunks = (int*)alloc(NB * 4);
  int* starts  = (int*)alloc(NB * (MAXC + 1) * 4);
  int* lens    = (int*)alloc(NB * MAXC * 4);
  u16* pooled  = (u16*)alloc((size_t)NB * MAXC * DM * 2);
  u16* chunks  = (u16*)alloc((size_t)NB * MAXC * DM * 2);
  u16* h1      = (u16*)alloc((size_t)NB * MAXC * 2 * DM * 2);
  float* h2    = (float*)alloc((size_t)NB * MAXC * DM * 4);
  (void)ws_size; (void)in_sizes; (void)n_in; (void)out_size;

  cvt5_bf16_kernel<<<2048, 256, 0, stream>>>(
      x, x_bf, NB * SEQ * DM / 4,
      wqkv, wqkv_bf, 3 * DM * DM / 4,
      wout, wout_bf, DM * DM / 4,
      w1, w1_bf, 2 * DM * DM / 4,
      w2, w2_bf, 2 * DM * DM / 4);

  segment_kernel<<<NB, 64, 0, stream>>>(bnd, nchunks, starts, lens);

  gemm256_kernel<<<(NB * SEQ / 256) * (QKVN / 256), 512, 0, stream>>>(
      x_bf, wqkv_bf, NB * SEQ, QKVN, DM, bqkv, qkv_bf);

  chunk_attn_kernel<<<dim3(NHEAD, MAXC, NB), 64, 0, stream>>>(
      qkv_bf, nchunks, starts, lens, pooled);

  gemm_bf16_kernel<2><<<dim3(DM / 128, NB * MAXC / 128), 256, 0, stream>>>(
      pooled, wout_bf, NB * MAXC, DM, DM, bout, chunks, nullptr, lens, semb, pos);

  gemm_bf16_kernel<3><<<dim3(2 * DM / 128, NB * MAXC / 128), 256, 0, stream>>>(
      chunks, w1_bf, NB * MAXC, 2 * DM, DM, b1, h1, nullptr, nullptr, nullptr, nullptr);

  gemm_bf16_kernel<4><<<dim3(DM / 128, NB * MAXC / 128), 256, 0, stream>>>(
      h1, w2_bf, NB * MAXC, DM, 2 * DM, b2, nullptr, h2, nullptr, nullptr, nullptr);

  ln_kernel<<<NB * MAXC, 256, 0, stream>>>(h2, lng, lnb, out);
}

// Round 10
// 344.988 us; speedup vs baseline: 1.2098x; 1.0216x over previous
//
#include <hip/hip_runtime.h>
#include <math.h>

// Problem constants
#define NB 8
#define SEQ 1024
#define DM 1536
#define NHEAD 12
#define DHEAD 128
#define MAXC 256
#define QKVN 4608
#define THRESH 0.85f

typedef unsigned short u16;
typedef __attribute__((ext_vector_type(8))) __bf16 bf16x8;
typedef __attribute__((ext_vector_type(4))) float f32x4;

struct __align__(4) U2 { u16 x, y; };
struct __align__(8) U4 { u16 x, y, z, w; };

__device__ __forceinline__ float bf2f(u16 u) {
  union { unsigned i; float f; } c; c.i = ((unsigned)u) << 16; return c.f;
}
__device__ __forceinline__ u16 f2bf(float f) {
  union { float f; unsigned i; } c; c.f = f;
  unsigned r = c.i + 0x7FFFu + ((c.i >> 16) & 1u);  // RNE
  return (u16)(r >> 16);
}

// ---------------------------------------------------------------- converts
__global__ __launch_bounds__(256) void cvt5_bf16_kernel(
    const float* __restrict__ i0, u16* __restrict__ o0, int n0,
    const float* __restrict__ i1, u16* __restrict__ o1, int n1,
    const float* __restrict__ i2, u16* __restrict__ o2, int n2,
    const float* __restrict__ i3, u16* __restrict__ o3, int n3,
    const float* __restrict__ i4, u16* __restrict__ o4, int n4) {
  const int stride = gridDim.x * blockDim.x;
  const int t0 = blockIdx.x * blockDim.x + threadIdx.x;
  const float* ins[5] = {i0, i1, i2, i3, i4};
  u16* outs[5] = {o0, o1, o2, o3, o4};
  const int ns[5] = {n0, n1, n2, n3, n4};
#pragma unroll
  for (int a = 0; a < 5; ++a) {
    const float* in = ins[a];
    u16* out = outs[a];
    for (int i = t0; i < ns[a]; i += stride) {
      float4 f = ((const float4*)in)[i];
      U4 u; u.x = f2bf(f.x); u.y = f2bf(f.y); u.z = f2bf(f.z); u.w = f2bf(f.w);
      ((U4*)out)[i] = u;
    }
  }
}

// ------------------------------------------------------------- segmentation
__global__ __launch_bounds__(64) void segment_kernel(
    const float* __restrict__ bnd, int* __restrict__ nchunks,
    int* __restrict__ starts, int* __restrict__ lens) {
  const int b = blockIdx.x;
  const int lane = threadIdx.x;
  int running = 0;
  for (int g = 0; g < SEQ / 64; ++g) {
    int s = g * 64 + lane;
    bool isb = bnd[b * SEQ + s] > THRESH;
    unsigned long long mask = __ballot(isb ? 1 : 0);
    int excl = __popcll(mask & ((1ULL << lane) - 1ULL));
    if (isb) {
      int c = running + excl;
      if (c <= MAXC) starts[b * (MAXC + 1) + c] = s;
    }
    running += __popcll(mask);
  }
  if (lane == 0) nchunks[b] = running;
  __syncthreads();
  int ncl = min(running, MAXC);
  for (int c = lane; c < MAXC; c += 64) {
    int v = 0;
    if (c < ncl) {
      int st = starts[b * (MAXC + 1) + c];
      int en = (c + 1 < running) ? starts[b * (MAXC + 1) + c + 1] : SEQ;
      v = en - st;
    }
    lens[b * MAXC + c] = v;
  }
}

// --------------------------------------------- 128x256 pipelined QKV GEMM
// 8 waves (2M x 4N), per-wave 64x64 output (4x4 frags, acc=64 VGPR).
// 3 LDS buffers x 24KB = 72KB -> 2 blocks/CU co-resident (m114 overlap:
// one block's MFMA fills the other's barrier/vmcnt stalls). Depth-2
// prefetch, counted vmcnt(3) (3 loads/thread/tile: 1 A + 2 B), one
// barrier/tile. Sigma LDS swizzle (conflict-free, coalescing-preserving).
__global__ __launch_bounds__(512, 4) void gemmQKV_kernel(
    const u16* __restrict__ A, const u16* __restrict__ B,
    const int M, const int N, const int K,
    const float* __restrict__ bias, u16* __restrict__ outB) {
  // per buffer: A = 4096 elems (8 groups*512), B = 8192 elems (16 groups*512)
  __shared__ __align__(16) u16 lds[3][12288];
  const int tid = threadIdx.x;
  const int wid = tid >> 6;
  const int lane = tid & 63;
  const int cpx = gridDim.x >> 3;
  const int bid = ((int)blockIdx.x & 7) * cpx + ((int)blockIdx.x >> 3);
  const int NX = N >> 8;                 // N / 256
  const int row0 = (bid / NX) << 7;      // *128
  const int col0 = (bid % NX) << 8;      // *256

  const int wr = wid >> 2;   // 0..1 (M half, 64 rows)
  const int wc = wid & 3;    // 0..3 (N quarter, 64 cols)
  const int rr = lane & 15;
  const int kg = lane >> 4;
  const int cw = rr * 4 + kg;
  const int slot = cw ^ ((cw >> 3) & 7);
  // staging decomposition (slot s -> group, sigma chunk)
  int srA, skA;                       // A: slot = tid
  { const int c = tid & 63; const int g = tid >> 6;
    const int gc = c ^ ((c >> 3) & 7);
    srA = g * 16 + (gc >> 2); skA = (gc & 3) * 8; }
  int srB[2], skB[2];                 // B: slot = i*512 + tid
#pragma unroll
  for (int i = 0; i < 2; ++i) {
    const int s = i * 512 + tid;
    const int c = s & 63; const int g = s >> 6;
    const int gc = c ^ ((c >> 3) & 7);
    srB[i] = g * 16 + (gc >> 2); skB[i] = (gc & 3) * 8;
  }

  const int NT = K >> 5;

#define STAGE(t)                                                              \
  {                                                                           \
    const int _b = (t) % 3;                                                   \
    const int _kb = (t) << 5;                                                 \
    u16* ga = const_cast<u16*>(A) + (size_t)(row0 + srA) * K + _kb + skA;     \
    __builtin_amdgcn_global_load_lds(                                         \
        (__attribute__((address_space(1))) void*)ga,                          \
        (__attribute__((address_space(3))) void*)&lds[_b][(wid * 64) * 8],    \
        16, 0, 0);                                                            \
    _Pragma("unroll") for (int i = 0; i < 2; ++i) {                           \
      u16* gb = const_cast<u16*>(B) + (size_t)(col0 + srB[i]) * K + _kb +     \
                skB[i];                                                       \
      __builtin_amdgcn_global_load_lds(                                       \
          (__attribute__((address_space(1))) void*)gb,                        \
          (__attribute__((address_space(3))) void*)&lds[_b]                   \
              [4096 + (i * 512 + wid * 64) * 8], 16, 0, 0);                   \
    }                                                                         \
  }

  f32x4 acc[4][4] = {};

  STAGE(0); STAGE(1);
  asm volatile("s_waitcnt vmcnt(3)" ::: "memory");
  __builtin_amdgcn_s_barrier();

  for (int t = 0; t < NT; ++t) {
    const int buf = t % 3;
    bf16x8 bf[4], af[4];
#pragma unroll
    for (int n = 0; n < 4; ++n)
      bf[n] = *(const bf16x8*)&lds[buf][4096 + ((wc * 4 + n) * 64 + slot) * 8];
#pragma unroll
    for (int m = 0; m < 4; ++m)
      af[m] = *(const bf16x8*)&lds[buf][((wr * 4 + m) * 64 + slot) * 8];
    if (t + 2 < NT) STAGE(t + 2);
    __builtin_amdgcn_s_setprio(1);
#pragma unroll
    for (int m = 0; m < 4; ++m)
#pragma unroll
      for (int n = 0; n < 4; ++n)
        acc[m][n] = __builtin_amdgcn_mfma_f32_16x16x32_bf16(af[m], bf[n], acc[m][n], 0, 0, 0);
    __builtin_amdgcn_s_setprio(0);
    if (t + 2 < NT) {
      asm volatile("s_waitcnt vmcnt(3)" ::: "memory");  // t+1 resident
    } else if (t + 1 < NT) {
      asm volatile("s_waitcnt vmcnt(0)" ::: "memory");
    }
    __builtin_amdgcn_s_barrier();
  }
#undef STAGE

#pragma unroll
  for (int m = 0; m < 4; ++m) {
#pragma unroll
    for (int n = 0; n < 4; ++n) {
      const int col = col0 + wc * 64 + n * 16 + rr;
      const float bs = bias[col];
#pragma unroll
      for (int j = 0; j < 4; ++j) {
        const int row = row0 + wr * 64 + m * 16 + (lane >> 4) * 4 + j;
        outB[(size_t)row * N + col] = f2bf(acc[m][n][j] + bs);
      }
    }
  }
}

// -------------------------------------------------------------- 128^2 GEMM
// 3-buffer depth-2 pipeline (48KB LDS -> 3 blocks/CU), counted vmcnt(4).
template <int MODE>
__global__ __launch_bounds__(256) void gemm_bf16_kernel(
    const u16* __restrict__ A, const u16* __restrict__ B,
    const int M, const int N, const int K,
    const float* __restrict__ bias,
    u16* __restrict__ outB, float* __restrict__ outF,
    const int* __restrict__ lens, const float* __restrict__ semb,
    const float* __restrict__ pos) {
  __shared__ __align__(16) u16 As[3][128 * 32];
  __shared__ __align__(16) u16 Bs[3][128 * 32];
  const int tid = threadIdx.x;
  const int wave = tid >> 6;
  const int lane = tid & 63;
  const int row0 = blockIdx.y * 128;
  const int col0 = blockIdx.x * 128;
  const int wm = (wave >> 1) * 64;
  const int wn = (wave & 1) * 64;
  const int gch = lane ^ ((lane >> 3) & 7);
  const int sr = gch >> 2;
  const int sc = (gch & 3) * 8;
  const int rr = lane & 15;
  const int kg = lane >> 4;
  const int cwant = rr * 4 + kg;
  const int slot = cwant ^ ((cwant >> 3) & 7);
  const int NT = K >> 5;
  f32x4 acc[4][4] = {};

#define STAGE128(t)                                                           \
  {                                                                           \
    const int _b = (t) % 3;                                                   \
    const int _k = (t) << 5;                                                  \
    _Pragma("unroll") for (int tt = 0; tt < 2; ++tt) {                        \
      const int li = wave * 2 + tt;                                           \
      u16* ga = const_cast<u16*>(A) + (size_t)(row0 + li * 16 + sr) * K +     \
                _k + sc;                                                      \
      u16* gb = const_cast<u16*>(B) + (size_t)(col0 + li * 16 + sr) * K +     \
                _k + sc;                                                      \
      __builtin_amdgcn_global_load_lds(                                       \
          (__attribute__((address_space(1))) void*)ga,                        \
          (__attribute__((address_space(3))) void*)(As[_b] + li * 512), 16,   \
          0, 0);                                                              \
      __builtin_amdgcn_global_load_lds(                                       \
          (__attribute__((address_space(1))) void*)gb,                        \
          (__attribute__((address_space(3))) void*)(Bs[_b] + li * 512), 16,   \
          0, 0);                                                              \
    }                                                                         \
  }

  STAGE128(0); STAGE128(1);
  asm volatile("s_waitcnt vmcnt(4)" ::: "memory");
  __builtin_amdgcn_s_barrier();

  for (int t = 0; t < NT; ++t) {
    const int cb = t % 3;
    bf16x8 bfr[4], af[4];
#pragma unroll
    for (int n = 0; n < 4; ++n)
      bfr[n] = *(const bf16x8*)(Bs[cb] + ((wn >> 4) + n) * 512 + slot * 8);
#pragma unroll
    for (int m = 0; m < 4; ++m)
      af[m] = *(const bf16x8*)(As[cb] + ((wm >> 4) + m) * 512 + slot * 8);
    if (t + 2 < NT) STAGE128(t + 2);
#pragma unroll
    for (int m = 0; m < 4; ++m)
#pragma unroll
      for (int n = 0; n < 4; ++n)
        acc[m][n] = __builtin_amdgcn_mfma_f32_16x16x32_bf16(af[m], bfr[n], acc[m][n], 0, 0, 0);
    if (t + 2 < NT) {
      asm volatile("s_waitcnt vmcnt(4)" ::: "memory");  // t+1 resident
    } else if (t + 1 < NT) {
      asm volatile("s_waitcnt vmcnt(0)" ::: "memory");
    }
    __builtin_amdgcn_s_barrier();
  }
#undef STAGE128

  const int rg = (lane >> 4) * 4;
#pragma unroll
  for (int m = 0; m < 4; ++m) {
#pragma unroll
    for (int n = 0; n < 4; ++n) {
      const int col = col0 + wn + n * 16 + rr;
#pragma unroll
      for (int j = 0; j < 4; ++j) {
        const int row = row0 + wm + m * 16 + rg + j;
        float v = acc[m][n][j];
        if (MODE == 2) {
          const int len = lens[row];
          float val = 0.f;
          if (len > 0) {
            const int si = len < 1023 ? len : 1023;
            val = v + bias[col] + semb[(size_t)si * DM + col];
          }
          val += pos[(size_t)(row & (MAXC - 1)) * DM + col];
          outB[(size_t)row * N + col] = f2bf(val);
        } else if (MODE == 3) {
          float z = v + bias[col];
          float gel = 0.5f * z * (1.f + erff(z * 0.70710678118654752440f));
          outB[(size_t)row * N + col] = f2bf(gel);
        } else {
          outF[(size_t)row * N + col] = v + bias[col];
        }
      }
    }
  }
}

// ----------------------------------------------------- chunk attention v5
// One wave per (h,c,b). Register-only L<=16 fast path (93% of chunks).
// V-pooling vectorized: 2 keys/iter, U4 (8B) V loads, shfl_xor(32) combine.
__global__ __launch_bounds__(64) void chunk_attn_kernel(
    const u16* __restrict__ qkv, const int* __restrict__ nchunks,
    const int* __restrict__ starts, const int* __restrict__ lens,
    u16* __restrict__ pooled) {
  __shared__ float g_lds[SEQ];
  const int h = blockIdx.x;
  const int c = blockIdx.y;
  const int b = blockIdx.z;
  const int lane = threadIdx.x;
  const int nc = min(nchunks[b], MAXC);
  u16* prow = pooled + ((size_t)(b * MAXC + c)) * DM + h * DHEAD;
  if (c >= nc) {  // empty chunk: pooled ctx = 0
    U2 z; z.x = 0; z.y = 0;
    *(U2*)(prow + lane * 2) = z;
    return;
  }
  const int s0 = starts[b * (MAXC + 1) + c];
  const int L = lens[b * MAXC + c];
  const u16* Qb = qkv + ((size_t)(b * SEQ + s0)) * QKVN + h * DHEAD;
  const u16* Kb = Qb + DM;
  const u16* Vb = Qb + 2 * DM;

  const int col = lane & 15;
  const int grp = lane >> 4;
  const float scale = 0.08838834764831845f;  // 1/sqrt(128)
  const int half = lane >> 5;       // key parity this lane pools
  const int dl4 = (lane & 31) * 4;  // dim base (4 dims/lane over 32 lanes)

  float a[4] = {0.f, 0.f, 0.f, 0.f};

  if (L <= 16) {
    // ---------------- register-only single-tile path
    const int rc = col < L ? col : (L - 1);
    bf16x8 qf[4], kf[4];
#pragma unroll
    for (int s = 0; s < 4; ++s) {
      qf[s] = *(const bf16x8*)(Qb + (size_t)rc * QKVN + s * 32 + grp * 8);
      kf[s] = *(const bf16x8*)(Kb + (size_t)rc * QKVN + s * 32 + grp * 8);
    }
    f32x4 sc = {0.f, 0.f, 0.f, 0.f};
#pragma unroll
    for (int s = 0; s < 4; ++s)
      sc = __builtin_amdgcn_mfma_f32_16x16x32_bf16(qf[s], kf[s], sc, 0, 0, 0);
    const bool kvalid = col < L;
    float g = 0.f;
#pragma unroll
    for (int j = 0; j < 4; ++j) {
      float sj = sc[j] * scale;
      float mv = kvalid ? sj : -3e38f;
      mv = fmaxf(mv, __shfl_xor(mv, 1));
      mv = fmaxf(mv, __shfl_xor(mv, 2));
      mv = fmaxf(mv, __shfl_xor(mv, 4));
      mv = fmaxf(mv, __shfl_xor(mv, 8));
      float pv = kvalid ? __expf(sj - mv) : 0.f;
      float dv = pv;
      dv += __shfl_xor(dv, 1);
      dv += __shfl_xor(dv, 2);
      dv += __shfl_xor(dv, 4);
      dv += __shfl_xor(dv, 8);
      const bool rv = (grp * 4 + j) < L;
      g += rv ? pv / dv : 0.f;
    }
    g += __shfl_xor(g, 16);
    g += __shfl_xor(g, 32);   // lanes 0-15 (replicated): column sums
    for (int j = 0; j < L; j += 2) {
      const int jj = j + half;
      const bool jv = jj < L;
      float gj = __shfl(g, jv ? jj : 0);
      if (!jv) gj = 0.f;
      const int jc = jv ? jj : 0;
      U4 vv = *(const U4*)(Vb + (size_t)jc * QKVN + dl4);
      a[0] += gj * bf2f(vv.x); a[1] += gj * bf2f(vv.y);
      a[2] += gj * bf2f(vv.z); a[3] += gj * bf2f(vv.w);
    }
  } else {
    // ---------------- general tiled path (wave-local LDS g, no barriers)
    float* gw = g_lds;
    for (int j = lane; j < L; j += 64) gw[j] = 0.f;
    const int NT = (L + 15) >> 4;
    for (int qt = 0; qt < NT; ++qt) {
      const int qr = qt * 16 + col;
      const int qrc = qr < L ? qr : (L - 1);
      bf16x8 qf[4];
#pragma unroll
      for (int s = 0; s < 4; ++s)
        qf[s] = *(const bf16x8*)(Qb + (size_t)qrc * QKVN + s * 32 + grp * 8);

      float m[4] = {-3e38f, -3e38f, -3e38f, -3e38f};
      float den[4] = {0.f, 0.f, 0.f, 0.f};
      for (int kt = 0; kt < NT; ++kt) {
        const int kr = kt * 16 + col;
        const bool kvalid = kr < L;
        const int krc = kvalid ? kr : (L - 1);
        f32x4 sc = {0.f, 0.f, 0.f, 0.f};
#pragma unroll
        for (int s = 0; s < 4; ++s) {
          bf16x8 kf = *(const bf16x8*)(Kb + (size_t)krc * QKVN + s * 32 + grp * 8);
          sc = __builtin_amdgcn_mfma_f32_16x16x32_bf16(qf[s], kf, sc, 0, 0, 0);
        }
#pragma unroll
        for (int j = 0; j < 4; ++j) {
          float sj = sc[j] * scale;
          float mv = kvalid ? sj : -3e38f;
          mv = fmaxf(mv, __shfl_xor(mv, 1));
          mv = fmaxf(mv, __shfl_xor(mv, 2));
          mv = fmaxf(mv, __shfl_xor(mv, 4));
          mv = fmaxf(mv, __shfl_xor(mv, 8));
          float mn = fmaxf(m[j], mv);
          float pv = kvalid ? __expf(sj - mn) : 0.f;
          pv += __shfl_xor(pv, 1);
          pv += __shfl_xor(pv, 2);
          pv += __shfl_xor(pv, 4);
          pv += __shfl_xor(pv, 8);
          den[j] = den[j] * __expf(m[j] - mn) + pv;
          m[j] = mn;
        }
      }
      float inv[4];
#pragma unroll
      for (int j = 0; j < 4; ++j) {
        const bool rv = (qt * 16 + grp * 4 + j) < L;
        inv[j] = rv ? 1.f / den[j] : 0.f;
      }
      for (int kt = 0; kt < NT; ++kt) {
        const int kr = kt * 16 + col;
        const bool kvalid = kr < L;
        const int krc = kvalid ? kr : (L - 1);
        f32x4 sc = {0.f, 0.f, 0.f, 0.f};
#pragma unroll
        for (int s = 0; s < 4; ++s) {
          bf16x8 kf = *(const bf16x8*)(Kb + (size_t)krc * QKVN + s * 32 + grp * 8);
          sc = __builtin_amdgcn_mfma_f32_16x16x32_bf16(qf[s], kf, sc, 0, 0, 0);
        }
        float colsum = 0.f;
#pragma unroll
        for (int j = 0; j < 4; ++j)
          colsum += __expf(sc[j] * scale - m[j]) * inv[j];
        colsum += __shfl_xor(colsum, 16);
        colsum += __shfl_xor(colsum, 32);
        if (grp == 0 && kvalid) gw[kt * 16 + col] += colsum;
      }
    }
    for (int j = 0; j < L; j += 2) {
      const int jj = j + half;
      const bool jv = jj < L;
      float gj = jv ? gw[jj] : 0.f;
      const int jc = jv ? jj : 0;
      U4 vv = *(const U4*)(Vb + (size_t)jc * QKVN + dl4);
      a[0] += gj * bf2f(vv.x); a[1] += gj * bf2f(vv.y);
      a[2] += gj * bf2f(vv.z); a[3] += gj * bf2f(vv.w);
    }
  }
  const float invL = 1.f / (float)L;
#pragma unroll
  for (int i = 0; i < 4; ++i) {
    a[i] += __shfl_xor(a[i], 32);
    a[i] *= invL;
  }
  if (lane < 32) {
    U4 r; r.x = f2bf(a[0]); r.y = f2bf(a[1]); r.z = f2bf(a[2]); r.w = f2bf(a[3]);
    *(U4*)(prow + dl4) = r;
  }
}

// ---------------------------------------------------------------- LayerNorm
__global__ __launch_bounds__(256) void ln_kernel(
    const float* __restrict__ h2, const float* __restrict__ gamma,
    const float* __restrict__ beta, float* __restrict__ out) {
  const int row = blockIdx.x;
  const float* x = h2 + (size_t)row * DM;
  float* o = out + (size_t)row * DM;
  const int tid = threadIdx.x;
  float v[6];
  float s = 0.f;
#pragma unroll
  for (int i = 0; i < 6; ++i) { v[i] = x[tid + i * 256]; s += v[i]; }
  __shared__ float red[8];
#pragma unroll
  for (int off = 32; off; off >>= 1) s += __shfl_xor(s, off);
  if ((tid & 63) == 0) red[tid >> 6] = s;
  __syncthreads();
  const float mu = (red[0] + red[1] + red[2] + red[3]) * (1.f / (float)DM);
  float vs = 0.f;
#pragma unroll
  for (int i = 0; i < 6; ++i) { float d = v[i] - mu; vs += d * d; }
#pragma unroll
  for (int off = 32; off; off >>= 1) vs += __shfl_xor(vs, off);
  __shared__ float red2[8];
  if ((tid & 63) == 0) red2[tid >> 6] = vs;
  __syncthreads();
  const float var = (red2[0] + red2[1] + red2[2] + red2[3]) * (1.f / (float)DM);
  const float inv = rsqrtf(var + 1e-5f);
#pragma unroll
  for (int i = 0; i < 6; ++i) {
    const int cidx = tid + i * 256;
    o[cidx] = (v[i] - mu) * inv * gamma[cidx] + beta[cidx];
  }
}

// ------------------------------------------------------------------ launch
extern "C" void kernel_launch(void* const* d_in, const int* in_sizes, int n_in,
                              void* d_out, int out_size, void* d_ws, size_t ws_size,
                              hipStream_t stream) {
  const float* x    = (const float*)d_in[0];
  const float* bnd  = (const float*)d_in[1];
  const float* wqkv = (const float*)d_in[2];
  const float* bqkv = (const float*)d_in[3];
  const float* wout = (const float*)d_in[4];
  const float* bout = (const float*)d_in[5];
  const float* w1   = (const float*)d_in[6];
  const float* b1   = (const float*)d_in[7];
  const float* w2   = (const float*)d_in[8];
  const float* b2   = (const float*)d_in[9];
  const float* lng  = (const float*)d_in[10];
  const float* lnb  = (const float*)d_in[11];
  const float* pos  = (const float*)d_in[12];
  const float* semb = (const float*)d_in[13];
  float* out = (float*)d_out;

  char* ws = (char*)d_ws;
  size_t off = 0;
  auto alloc = [&](size_t bytes) -> char* {
    char* p = ws + off;
    off += (bytes + 255) & ~(size_t)255;
    return p;
  };
  u16* x_bf    = (u16*)alloc((size_t)NB * SEQ * DM * 2);
  u16* wqkv_bf = (u16*)alloc((size_t)3 * DM * DM * 2);
  u16* wout_bf = (u16*)alloc((size_t)DM * DM * 2);
  u16* w1_bf   = (u16*)alloc((size_t)2 * DM * DM * 2);
  u16* w2_bf   = (u16*)alloc((size_t)2 * DM * DM * 2);
  u16* qkv_bf  = (u16*)alloc((size_t)NB * SEQ * QKVN * 2);
  int* nchunks = (int*)alloc(NB * 4);
  int* starts  = (int*)alloc(NB * (MAXC + 1) * 4);
  int* lens    = (int*)alloc(NB * MAXC * 4);
  u16* pooled  = (u16*)alloc((size_t)NB * MAXC * DM * 2);
  u16* chunks  = (u16*)alloc((size_t)NB * MAXC * DM * 2);
  u16* h1      = (u16*)alloc((size_t)NB * MAXC * 2 * DM * 2);
  float* h2    = (float*)alloc((size_t)NB * MAXC * DM * 4);
  (void)ws_size; (void)in_sizes; (void)n_in; (void)out_size;

  cvt5_bf16_kernel<<<2048, 256, 0, stream>>>(
      x, x_bf, NB * SEQ * DM / 4,
      wqkv, wqkv_bf, 3 * DM * DM / 4,
      wout, wout_bf, DM * DM / 4,
      w1, w1_bf, 2 * DM * DM / 4,
      w2, w2_bf, 2 * DM * DM / 4);

  segment_kernel<<<NB, 64, 0, stream>>>(bnd, nchunks, starts, lens);

  // QKV projection: [8192,1536] @ [4608,1536]^T, 128x256 tiles, 2 blocks/CU
  gemmQKV_kernel<<<(NB * SEQ / 128) * (QKVN / 256), 512, 0, stream>>>(
      x_bf, wqkv_bf, NB * SEQ, QKVN, DM, bqkv, qkv_bf);

  chunk_attn_kernel<<<dim3(NHEAD, MAXC, NB), 64, 0, stream>>>(
      qkv_bf, nchunks, starts, lens, pooled);

  gemm_bf16_kernel<2><<<dim3(DM / 128, NB * MAXC / 128), 256, 0, stream>>>(
      pooled, wout_bf, NB * MAXC, DM, DM, bout, chunks, nullptr, lens, semb, pos);

  gemm_bf16_kernel<3><<<dim3(2 * DM / 128, NB * MAXC / 128), 256, 0, stream>>>(
      chunks, w1_bf, NB * MAXC, 2 * DM, DM, b1, h1, nullptr, nullptr, nullptr, nullptr);

  gemm_bf16_kernel<4><<<dim3(DM / 128, NB * MAXC / 128), 256, 0, stream>>>(
      h1, w2_bf, NB * MAXC, DM, 2 * DM, b2, nullptr, h2, nullptr, nullptr, nullptr);

  ln_kernel<<<NB * MAXC, 256, 0, stream>>>(h2, lng, lnb, out);
}

// Round 12
// 323.650 us; speedup vs baseline: 1.2895x; 1.0659x over previous
//
#include <hip/hip_runtime.h>
#include <math.h>

// Problem constants
#define NB 8
#define SEQ 1024
#define DM 1536
#define NHEAD 12
#define DHEAD 128
#define MAXC 256
#define QKVN 4608
#define THRESH 0.85f

typedef unsigned short u16;
typedef __attribute__((ext_vector_type(8))) __bf16 bf16x8;
typedef __attribute__((ext_vector_type(4))) float f32x4;

struct __align__(4) U2 { u16 x, y; };
struct __align__(8) U4 { u16 x, y, z, w; };

__device__ __forceinline__ float bf2f(u16 u) {
  union { unsigned i; float f; } c; c.i = ((unsigned)u) << 16; return c.f;
}
__device__ __forceinline__ u16 f2bf(float f) {
  union { float f; unsigned i; } c; c.f = f;
  unsigned r = c.i + 0x7FFFu + ((c.i >> 16) & 1u);  // RNE
  return (u16)(r >> 16);
}

// ---------------------------------------------------------------- converts
__global__ __launch_bounds__(256) void cvt5_bf16_kernel(
    const float* __restrict__ i0, u16* __restrict__ o0, int n0,
    const float* __restrict__ i1, u16* __restrict__ o1, int n1,
    const float* __restrict__ i2, u16* __restrict__ o2, int n2,
    const float* __restrict__ i3, u16* __restrict__ o3, int n3,
    const float* __restrict__ i4, u16* __restrict__ o4, int n4) {
  const int stride = gridDim.x * blockDim.x;
  const int t0 = blockIdx.x * blockDim.x + threadIdx.x;
  const float* ins[5] = {i0, i1, i2, i3, i4};
  u16* outs[5] = {o0, o1, o2, o3, o4};
  const int ns[5] = {n0, n1, n2, n3, n4};
#pragma unroll
  for (int a = 0; a < 5; ++a) {
    const float* in = ins[a];
    u16* out = outs[a];
    for (int i = t0; i < ns[a]; i += stride) {
      float4 f = ((const float4*)in)[i];
      U4 u; u.x = f2bf(f.x); u.y = f2bf(f.y); u.z = f2bf(f.z); u.w = f2bf(f.w);
      ((U4*)out)[i] = u;
    }
  }
}

// ------------------------------------------------------------- segmentation
__global__ __launch_bounds__(64) void segment_kernel(
    const float* __restrict__ bnd, int* __restrict__ nchunks,
    int* __restrict__ starts, int* __restrict__ lens) {
  const int b = blockIdx.x;
  const int lane = threadIdx.x;
  int running = 0;
  for (int g = 0; g < SEQ / 64; ++g) {
    int s = g * 64 + lane;
    bool isb = bnd[b * SEQ + s] > THRESH;
    unsigned long long mask = __ballot(isb ? 1 : 0);
    int excl = __popcll(mask & ((1ULL << lane) - 1ULL));
    if (isb) {
      int c = running + excl;
      if (c <= MAXC) starts[b * (MAXC + 1) + c] = s;
    }
    running += __popcll(mask);
  }
  if (lane == 0) nchunks[b] = running;
  __syncthreads();
  int ncl = min(running, MAXC);
  for (int c = lane; c < MAXC; c += 64) {
    int v = 0;
    if (c < ncl) {
      int st = starts[b * (MAXC + 1) + c];
      int en = (c + 1 < running) ? starts[b * (MAXC + 1) + c + 1] : SEQ;
      v = en - st;
    }
    lens[b * MAXC + c] = v;
  }
}

// --------------------------------------------- 128x256 pipelined QKV GEMM
// (R10-proven, byte-identical.) 8 waves (2Mx4N), per-wave 64x64, 3 LDS
// buffers x 24KB = 72KB -> 2 blocks/CU. Depth-2 prefetch, counted vmcnt(3)
// (3 uniform global_load_lds per thread per tile: 1 A + 2 B), one barrier
// per tile. Sigma LDS swizzle. ALL staging is single-type LDS-DMA (R11
// lesson: never mix reg-loads into a counted vmcnt ledger).
__global__ __launch_bounds__(512, 4) void gemmQKV_kernel(
    const u16* __restrict__ A, const u16* __restrict__ B,
    const int M, const int N, const int K,
    const float* __restrict__ bias, u16* __restrict__ outB) {
  __shared__ __align__(16) u16 lds[3][12288];
  const int tid = threadIdx.x;
  const int wid = tid >> 6;
  const int lane = tid & 63;
  const int cpx = gridDim.x >> 3;
  const int bid = ((int)blockIdx.x & 7) * cpx + ((int)blockIdx.x >> 3);
  const int NX = N >> 8;
  const int row0 = (bid / NX) << 7;
  const int col0 = (bid % NX) << 8;

  const int wr = wid >> 2;
  const int wc = wid & 3;
  const int rr = lane & 15;
  const int kg = lane >> 4;
  const int cw = rr * 4 + kg;
  const int slot = cw ^ ((cw >> 3) & 7);
  int srA, skA;
  { const int c = tid & 63; const int g = tid >> 6;
    const int gc = c ^ ((c >> 3) & 7);
    srA = g * 16 + (gc >> 2); skA = (gc & 3) * 8; }
  int srB[2], skB[2];
#pragma unroll
  for (int i = 0; i < 2; ++i) {
    const int s = i * 512 + tid;
    const int c = s & 63; const int g = s >> 6;
    const int gc = c ^ ((c >> 3) & 7);
    srB[i] = g * 16 + (gc >> 2); skB[i] = (gc & 3) * 8;
  }

  const int NT = K >> 5;

#define STAGE(t)                                                              \
  {                                                                           \
    const int _b = (t) % 3;                                                   \
    const int _kb = (t) << 5;                                                 \
    u16* ga = const_cast<u16*>(A) + (size_t)(row0 + srA) * K + _kb + skA;     \
    __builtin_amdgcn_global_load_lds(                                         \
        (__attribute__((address_space(1))) void*)ga,                          \
        (__attribute__((address_space(3))) void*)&lds[_b][(wid * 64) * 8],    \
        16, 0, 0);                                                            \
    _Pragma("unroll") for (int i = 0; i < 2; ++i) {                           \
      u16* gb = const_cast<u16*>(B) + (size_t)(col0 + srB[i]) * K + _kb +     \
                skB[i];                                                       \
      __builtin_amdgcn_global_load_lds(                                       \
          (__attribute__((address_space(1))) void*)gb,                        \
          (__attribute__((address_space(3))) void*)&lds[_b]                   \
              [4096 + (i * 512 + wid * 64) * 8], 16, 0, 0);                   \
    }                                                                         \
  }

  f32x4 acc[4][4] = {};

  STAGE(0); STAGE(1);
  asm volatile("s_waitcnt vmcnt(3)" ::: "memory");
  __builtin_amdgcn_s_barrier();

  for (int t = 0; t < NT; ++t) {
    const int buf = t % 3;
    bf16x8 bf[4], af[4];
#pragma unroll
    for (int n = 0; n < 4; ++n)
      bf[n] = *(const bf16x8*)&lds[buf][4096 + ((wc * 4 + n) * 64 + slot) * 8];
#pragma unroll
    for (int m = 0; m < 4; ++m)
      af[m] = *(const bf16x8*)&lds[buf][((wr * 4 + m) * 64 + slot) * 8];
    if (t + 2 < NT) STAGE(t + 2);
    __builtin_amdgcn_s_setprio(1);
#pragma unroll
    for (int m = 0; m < 4; ++m)
#pragma unroll
      for (int n = 0; n < 4; ++n)
        acc[m][n] = __builtin_amdgcn_mfma_f32_16x16x32_bf16(af[m], bf[n], acc[m][n], 0, 0, 0);
    __builtin_amdgcn_s_setprio(0);
    if (t + 2 < NT) {
      asm volatile("s_waitcnt vmcnt(3)" ::: "memory");
    } else if (t + 1 < NT) {
      asm volatile("s_waitcnt vmcnt(0)" ::: "memory");
    }
    __builtin_amdgcn_s_barrier();
  }
#undef STAGE

#pragma unroll
  for (int m = 0; m < 4; ++m) {
#pragma unroll
    for (int n = 0; n < 4; ++n) {
      const int col = col0 + wc * 64 + n * 16 + rr;
      const float bs = bias[col];
#pragma unroll
      for (int j = 0; j < 4; ++j) {
        const int row = row0 + wr * 64 + m * 16 + (lane >> 4) * 4 + j;
        outB[(size_t)row * N + col] = f2bf(acc[m][n][j] + bs);
      }
    }
  }
}

// ------------------------------------------------------------ 128x64 GEMM
// Small-GEMM tile shrunk 128x128 -> 128x64 to fix CU starvation (grids
// 192/384/192 -> 384/768/384 blocks; 36KB LDS + 32-VGPR acc -> 4 blocks/CU).
// Same proven 3-buffer depth-2 counted-vmcnt template (parameter change
// only): 3 uniform global_load_lds per thread per tile (2 A + 1 B);
// prologue vmcnt(3); steady vmcnt(3); tail vmcnt(0). Sigma swizzle.
template <int MODE>
__global__ __launch_bounds__(256, 4) void gemm_bf16_kernel(
    const u16* __restrict__ A, const u16* __restrict__ B,
    const int M, const int N, const int K,
    const float* __restrict__ bias,
    u16* __restrict__ outB, float* __restrict__ outF,
    const int* __restrict__ lens, const float* __restrict__ semb,
    const float* __restrict__ pos) {
  __shared__ __align__(16) u16 As[3][128 * 32];  // 8KB/buf
  __shared__ __align__(16) u16 Bs[3][64 * 32];   // 4KB/buf
  const int tid = threadIdx.x;
  const int wave = tid >> 6;
  const int lane = tid & 63;
  const int row0 = blockIdx.y * 128;
  const int col0 = blockIdx.x * 64;
  const int wm = (wave >> 1) * 64;   // 0 / 64
  const int wn = (wave & 1) * 32;    // 0 / 32
  const int gch = lane ^ ((lane >> 3) & 7);
  const int sr = gch >> 2;
  const int sc = (gch & 3) * 8;
  const int rr = lane & 15;
  const int kg = lane >> 4;
  const int cwant = rr * 4 + kg;
  const int slot = cwant ^ ((cwant >> 3) & 7);
  const int NT = K >> 5;
  f32x4 acc[4][2] = {};

#define STAGE64(t)                                                            \
  {                                                                           \
    const int _b = (t) % 3;                                                   \
    const int _k = (t) << 5;                                                  \
    _Pragma("unroll") for (int tt = 0; tt < 2; ++tt) {                        \
      const int li = wave * 2 + tt;                                           \
      u16* ga = const_cast<u16*>(A) + (size_t)(row0 + li * 16 + sr) * K +     \
                _k + sc;                                                      \
      __builtin_amdgcn_global_load_lds(                                       \
          (__attribute__((address_space(1))) void*)ga,                        \
          (__attribute__((address_space(3))) void*)(As[_b] + li * 512), 16,   \
          0, 0);                                                              \
    }                                                                         \
    u16* gb = const_cast<u16*>(B) + (size_t)(col0 + wave * 16 + sr) * K +     \
              _k + sc;                                                        \
    __builtin_amdgcn_global_load_lds(                                         \
        (__attribute__((address_space(1))) void*)gb,                          \
        (__attribute__((address_space(3))) void*)(Bs[_b] + wave * 512), 16,   \
        0, 0);                                                                \
  }

  STAGE64(0); STAGE64(1);
  asm volatile("s_waitcnt vmcnt(3)" ::: "memory");
  __builtin_amdgcn_s_barrier();

  for (int t = 0; t < NT; ++t) {
    const int cb = t % 3;
    bf16x8 bfr[2], af[4];
#pragma unroll
    for (int n = 0; n < 2; ++n)
      bfr[n] = *(const bf16x8*)(Bs[cb] + ((wn >> 4) + n) * 512 + slot * 8);
#pragma unroll
    for (int m = 0; m < 4; ++m)
      af[m] = *(const bf16x8*)(As[cb] + ((wm >> 4) + m) * 512 + slot * 8);
    if (t + 2 < NT) STAGE64(t + 2);
#pragma unroll
    for (int m = 0; m < 4; ++m)
#pragma unroll
      for (int n = 0; n < 2; ++n)
        acc[m][n] = __builtin_amdgcn_mfma_f32_16x16x32_bf16(af[m], bfr[n], acc[m][n], 0, 0, 0);
    if (t + 2 < NT) {
      asm volatile("s_waitcnt vmcnt(3)" ::: "memory");
    } else if (t + 1 < NT) {
      asm volatile("s_waitcnt vmcnt(0)" ::: "memory");
    }
    __builtin_amdgcn_s_barrier();
  }
#undef STAGE64

  const int rg = (lane >> 4) * 4;
#pragma unroll
  for (int m = 0; m < 4; ++m) {
#pragma unroll
    for (int n = 0; n < 2; ++n) {
      const int col = col0 + wn + n * 16 + rr;
#pragma unroll
      for (int j = 0; j < 4; ++j) {
        const int row = row0 + wm + m * 16 + rg + j;
        float v = acc[m][n][j];
        if (MODE == 2) {
          const int len = lens[row];
          float val = 0.f;
          if (len > 0) {
            const int si = len < 1023 ? len : 1023;
            val = v + bias[col] + semb[(size_t)si * DM + col];
          }
          val += pos[(size_t)(row & (MAXC - 1)) * DM + col];
          outB[(size_t)row * N + col] = f2bf(val);
        } else if (MODE == 3) {
          float z = v + bias[col];
          float gel = 0.5f * z * (1.f + erff(z * 0.70710678118654752440f));
          outB[(size_t)row * N + col] = f2bf(gel);
        } else {
          outF[(size_t)row * N + col] = v + bias[col];
        }
      }
    }
  }
}

// ----------------------------------------------------- chunk attention v5
// One wave per (h,c,b). Register-only L<=16 fast path (93% of chunks).
// V-pooling vectorized: 2 keys/iter, U4 (8B) V loads, shfl_xor(32) combine.
__global__ __launch_bounds__(64) void chunk_attn_kernel(
    const u16* __restrict__ qkv, const int* __restrict__ nchunks,
    const int* __restrict__ starts, const int* __restrict__ lens,
    u16* __restrict__ pooled) {
  __shared__ float g_lds[SEQ];
  const int h = blockIdx.x;
  const int c = blockIdx.y;
  const int b = blockIdx.z;
  const int lane = threadIdx.x;
  const int nc = min(nchunks[b], MAXC);
  u16* prow = pooled + ((size_t)(b * MAXC + c)) * DM + h * DHEAD;
  if (c >= nc) {  // empty chunk: pooled ctx = 0
    U2 z; z.x = 0; z.y = 0;
    *(U2*)(prow + lane * 2) = z;
    return;
  }
  const int s0 = starts[b * (MAXC + 1) + c];
  const int L = lens[b * MAXC + c];
  const u16* Qb = qkv + ((size_t)(b * SEQ + s0)) * QKVN + h * DHEAD;
  const u16* Kb = Qb + DM;
  const u16* Vb = Qb + 2 * DM;

  const int col = lane & 15;
  const int grp = lane >> 4;
  const float scale = 0.08838834764831845f;  // 1/sqrt(128)
  const int half = lane >> 5;
  const int dl4 = (lane & 31) * 4;

  float a[4] = {0.f, 0.f, 0.f, 0.f};

  if (L <= 16) {
    const int rc = col < L ? col : (L - 1);
    bf16x8 qf[4], kf[4];
#pragma unroll
    for (int s = 0; s < 4; ++s) {
      qf[s] = *(const bf16x8*)(Qb + (size_t)rc * QKVN + s * 32 + grp * 8);
      kf[s] = *(const bf16x8*)(Kb + (size_t)rc * QKVN + s * 32 + grp * 8);
    }
    f32x4 sc = {0.f, 0.f, 0.f, 0.f};
#pragma unroll
    for (int s = 0; s < 4; ++s)
      sc = __builtin_amdgcn_mfma_f32_16x16x32_bf16(qf[s], kf[s], sc, 0, 0, 0);
    const bool kvalid = col < L;
    float g = 0.f;
#pragma unroll
    for (int j = 0; j < 4; ++j) {
      float sj = sc[j] * scale;
      float mv = kvalid ? sj : -3e38f;
      mv = fmaxf(mv, __shfl_xor(mv, 1));
      mv = fmaxf(mv, __shfl_xor(mv, 2));
      mv = fmaxf(mv, __shfl_xor(mv, 4));
      mv = fmaxf(mv, __shfl_xor(mv, 8));
      float pv = kvalid ? __expf(sj - mv) : 0.f;
      float dv = pv;
      dv += __shfl_xor(dv, 1);
      dv += __shfl_xor(dv, 2);
      dv += __shfl_xor(dv, 4);
      dv += __shfl_xor(dv, 8);
      const bool rv = (grp * 4 + j) < L;
      g += rv ? pv / dv : 0.f;
    }
    g += __shfl_xor(g, 16);
    g += __shfl_xor(g, 32);
    for (int j = 0; j < L; j += 2) {
      const int jj = j + half;
      const bool jv = jj < L;
      float gj = __shfl(g, jv ? jj : 0);
      if (!jv) gj = 0.f;
      const int jc = jv ? jj : 0;
      U4 vv = *(const U4*)(Vb + (size_t)jc * QKVN + dl4);
      a[0] += gj * bf2f(vv.x); a[1] += gj * bf2f(vv.y);
      a[2] += gj * bf2f(vv.z); a[3] += gj * bf2f(vv.w);
    }
  } else {
    float* gw = g_lds;
    for (int j = lane; j < L; j += 64) gw[j] = 0.f;
    const int NT = (L + 15) >> 4;
    for (int qt = 0; qt < NT; ++qt) {
      const int qr = qt * 16 + col;
      const int qrc = qr < L ? qr : (L - 1);
      bf16x8 qf[4];
#pragma unroll
      for (int s = 0; s < 4; ++s)
        qf[s] = *(const bf16x8*)(Qb + (size_t)qrc * QKVN + s * 32 + grp * 8);

      float m[4] = {-3e38f, -3e38f, -3e38f, -3e38f};
      float den[4] = {0.f, 0.f, 0.f, 0.f};
      for (int kt = 0; kt < NT; ++kt) {
        const int kr = kt * 16 + col;
        const bool kvalid = kr < L;
        const int krc = kvalid ? kr : (L - 1);
        f32x4 sc = {0.f, 0.f, 0.f, 0.f};
#pragma unroll
        for (int s = 0; s < 4; ++s) {
          bf16x8 kf = *(const bf16x8*)(Kb + (size_t)krc * QKVN + s * 32 + grp * 8);
          sc = __builtin_amdgcn_mfma_f32_16x16x32_bf16(qf[s], kf, sc, 0, 0, 0);
        }
#pragma unroll
        for (int j = 0; j < 4; ++j) {
          float sj = sc[j] * scale;
          float mv = kvalid ? sj : -3e38f;
          mv = fmaxf(mv, __shfl_xor(mv, 1));
          mv = fmaxf(mv, __shfl_xor(mv, 2));
          mv = fmaxf(mv, __shfl_xor(mv, 4));
          mv = fmaxf(mv, __shfl_xor(mv, 8));
          float mn = fmaxf(m[j], mv);
          float pv = kvalid ? __expf(sj - mn) : 0.f;
          pv += __shfl_xor(pv, 1);
          pv += __shfl_xor(pv, 2);
          pv += __shfl_xor(pv, 4);
          pv += __shfl_xor(pv, 8);
          den[j] = den[j] * __expf(m[j] - mn) + pv;
          m[j] = mn;
        }
      }
      float inv[4];
#pragma unroll
      for (int j = 0; j < 4; ++j) {
        const bool rv = (qt * 16 + grp * 4 + j) < L;
        inv[j] = rv ? 1.f / den[j] : 0.f;
      }
      for (int kt = 0; kt < NT; ++kt) {
        const int kr = kt * 16 + col;
        const bool kvalid = kr < L;
        const int krc = kvalid ? kr : (L - 1);
        f32x4 sc = {0.f, 0.f, 0.f, 0.f};
#pragma unroll
        for (int s = 0; s < 4; ++s) {
          bf16x8 kf = *(const bf16x8*)(Kb + (size_t)krc * QKVN + s * 32 + grp * 8);
          sc = __builtin_amdgcn_mfma_f32_16x16x32_bf16(qf[s], kf, sc, 0, 0, 0);
        }
        float colsum = 0.f;
#pragma unroll
        for (int j = 0; j < 4; ++j)
          colsum += __expf(sc[j] * scale - m[j]) * inv[j];
        colsum += __shfl_xor(colsum, 16);
        colsum += __shfl_xor(colsum, 32);
        if (grp == 0 && kvalid) gw[kt * 16 + col] += colsum;
      }
    }
    for (int j = 0; j < L; j += 2) {
      const int jj = j + half;
      const bool jv = jj < L;
      float gj = jv ? gw[jj] : 0.f;
      const int jc = jv ? jj : 0;
      U4 vv = *(const U4*)(Vb + (size_t)jc * QKVN + dl4);
      a[0] += gj * bf2f(vv.x); a[1] += gj * bf2f(vv.y);
      a[2] += gj * bf2f(vv.z); a[3] += gj * bf2f(vv.w);
    }
  }
  const float invL = 1.f / (float)L;
#pragma unroll
  for (int i = 0; i < 4; ++i) {
    a[i] += __shfl_xor(a[i], 32);
    a[i] *= invL;
  }
  if (lane < 32) {
    U4 r; r.x = f2bf(a[0]); r.y = f2bf(a[1]); r.z = f2bf(a[2]); r.w = f2bf(a[3]);
    *(U4*)(prow + dl4) = r;
  }
}

// ---------------------------------------------------------------- LayerNorm
__global__ __launch_bounds__(256) void ln_kernel(
    const float* __restrict__ h2, const float* __restrict__ gamma,
    const float* __restrict__ beta, float* __restrict__ out) {
  const int row = blockIdx.x;
  const float* x = h2 + (size_t)row * DM;
  float* o = out + (size_t)row * DM;
  const int tid = threadIdx.x;
  float v[6];
  float s = 0.f;
#pragma unroll
  for (int i = 0; i < 6; ++i) { v[i] = x[tid + i * 256]; s += v[i]; }
  __shared__ float red[8];
#pragma unroll
  for (int off = 32; off; off >>= 1) s += __shfl_xor(s, off);
  if ((tid & 63) == 0) red[tid >> 6] = s;
  __syncthreads();
  const float mu = (red[0] + red[1] + red[2] + red[3]) * (1.f / (float)DM);
  float vs = 0.f;
#pragma unroll
  for (int i = 0; i < 6; ++i) { float d = v[i] - mu; vs += d * d; }
#pragma unroll
  for (int off = 32; off; off >>= 1) vs += __shfl_xor(vs, off);
  __shared__ float red2[8];
  if ((tid & 63) == 0) red2[tid >> 6] = vs;
  __syncthreads();
  const float var = (red2[0] + red2[1] + red2[2] + red2[3]) * (1.f / (float)DM);
  const float inv = rsqrtf(var + 1e-5f);
#pragma unroll
  for (int i = 0; i < 6; ++i) {
    const int cidx = tid + i * 256;
    o[cidx] = (v[i] - mu) * inv * gamma[cidx] + beta[cidx];
  }
}

// ------------------------------------------------------------------ launch
extern "C" void kernel_launch(void* const* d_in, const int* in_sizes, int n_in,
                              void* d_out, int out_size, void* d_ws, size_t ws_size,
                              hipStream_t stream) {
  const float* x    = (const float*)d_in[0];
  const float* bnd  = (const float*)d_in[1];
  const float* wqkv = (const float*)d_in[2];
  const float* bqkv = (const float*)d_in[3];
  const float* wout = (const float*)d_in[4];
  const float* bout = (const float*)d_in[5];
  const float* w1   = (const float*)d_in[6];
  const float* b1   = (const float*)d_in[7];
  const float* w2   = (const float*)d_in[8];
  const float* b2   = (const float*)d_in[9];
  const float* lng  = (const float*)d_in[10];
  const float* lnb  = (const float*)d_in[11];
  const float* pos  = (const float*)d_in[12];
  const float* semb = (const float*)d_in[13];
  float* out = (float*)d_out;

  char* ws = (char*)d_ws;
  size_t off = 0;
  auto alloc = [&](size_t bytes) -> char* {
    char* p = ws + off;
    off += (bytes + 255) & ~(size_t)255;
    return p;
  };
  u16* x_bf    = (u16*)alloc((size_t)NB * SEQ * DM * 2);
  u16* wqkv_bf = (u16*)alloc((size_t)3 * DM * DM * 2);
  u16* wout_bf = (u16*)alloc((size_t)DM * DM * 2);
  u16* w1_bf   = (u16*)alloc((size_t)2 * DM * DM * 2);
  u16* w2_bf   = (u16*)alloc((size_t)2 * DM * DM * 2);
  u16* qkv_bf  = (u16*)alloc((size_t)NB * SEQ * QKVN * 2);
  int* nchunks = (int*)alloc(NB * 4);
  int* starts  = (int*)alloc(NB * (MAXC + 1) * 4);
  int* lens    = (int*)alloc(NB * MAXC * 4);
  u16* pooled  = (u16*)alloc((size_t)NB * MAXC * DM * 2);
  u16* chunks  = (u16*)alloc((size_t)NB * MAXC * DM * 2);
  u16* h1      = (u16*)alloc((size_t)NB * MAXC * 2 * DM * 2);
  float* h2    = (float*)alloc((size_t)NB * MAXC * DM * 4);
  (void)ws_size; (void)in_sizes; (void)n_in; (void)out_size;

  cvt5_bf16_kernel<<<2048, 256, 0, stream>>>(
      x, x_bf, NB * SEQ * DM / 4,
      wqkv, wqkv_bf, 3 * DM * DM / 4,
      wout, wout_bf, DM * DM / 4,
      w1, w1_bf, 2 * DM * DM / 4,
      w2, w2_bf, 2 * DM * DM / 4);

  segment_kernel<<<NB, 64, 0, stream>>>(bnd, nchunks, starts, lens);

  // QKV projection: [8192,1536] @ [4608,1536]^T, 128x256 tiles, 2 blocks/CU
  gemmQKV_kernel<<<(NB * SEQ / 128) * (QKVN / 256), 512, 0, stream>>>(
      x_bf, wqkv_bf, NB * SEQ, QKVN, DM, bqkv, qkv_bf);

  chunk_attn_kernel<<<dim3(NHEAD, MAXC, NB), 64, 0, stream>>>(
      qkv_bf, nchunks, starts, lens, pooled);

  gemm_bf16_kernel<2><<<dim3(DM / 64, NB * MAXC / 128), 256, 0, stream>>>(
      pooled, wout_bf, NB * MAXC, DM, DM, bout, chunks, nullptr, lens, semb, pos);

  gemm_bf16_kernel<3><<<dim3(2 * DM / 64, NB * MAXC / 128), 256, 0, stream>>>(
      chunks, w1_bf, NB * MAXC, 2 * DM, DM, b1, h1, nullptr, nullptr, nullptr, nullptr);

  gemm_bf16_kernel<4><<<dim3(DM / 64, NB * MAXC / 128), 256, 0, stream>>>(
      h1, w2_bf, NB * MAXC, DM, 2 * DM, b2, nullptr, h2, nullptr, nullptr, nullptr);

  ln_kernel<<<NB * MAXC, 256, 0, stream>>>(h2, lng, lnb, out);
}

// Round 13
// 322.612 us; speedup vs baseline: 1.2937x; 1.0032x over previous
//
#include <hip/hip_runtime.h>
#include <math.h>

// Problem constants
#define NB 8
#define SEQ 1024
#define DM 1536
#define NHEAD 12
#define DHEAD 128
#define MAXC 256
#define QKVN 4608
#define THRESH 0.85f

typedef unsigned short u16;
typedef __attribute__((ext_vector_type(8))) __bf16 bf16x8;
typedef __attribute__((ext_vector_type(4))) float f32x4;

struct __align__(4) U2 { u16 x, y; };
struct __align__(8) U4 { u16 x, y, z, w; };

__device__ __forceinline__ float bf2f(u16 u) {
  union { unsigned i; float f; } c; c.i = ((unsigned)u) << 16; return c.f;
}
__device__ __forceinline__ u16 f2bf(float f) {
  union { float f; unsigned i; } c; c.f = f;
  unsigned r = c.i + 0x7FFFu + ((c.i >> 16) & 1u);  // RNE
  return (u16)(r >> 16);
}

// ---------------------------------------------------------------- converts
__global__ __launch_bounds__(256) void cvt5_bf16_kernel(
    const float* __restrict__ i0, u16* __restrict__ o0, int n0,
    const float* __restrict__ i1, u16* __restrict__ o1, int n1,
    const float* __restrict__ i2, u16* __restrict__ o2, int n2,
    const float* __restrict__ i3, u16* __restrict__ o3, int n3,
    const float* __restrict__ i4, u16* __restrict__ o4, int n4) {
  const int stride = gridDim.x * blockDim.x;
  const int t0 = blockIdx.x * blockDim.x + threadIdx.x;
  const float* ins[5] = {i0, i1, i2, i3, i4};
  u16* outs[5] = {o0, o1, o2, o3, o4};
  const int ns[5] = {n0, n1, n2, n3, n4};
#pragma unroll
  for (int a = 0; a < 5; ++a) {
    const float* in = ins[a];
    u16* out = outs[a];
    for (int i = t0; i < ns[a]; i += stride) {
      float4 f = ((const float4*)in)[i];
      U4 u; u.x = f2bf(f.x); u.y = f2bf(f.y); u.z = f2bf(f.z); u.w = f2bf(f.w);
      ((U4*)out)[i] = u;
    }
  }
}

// ------------------------------------------------------------- segmentation
__global__ __launch_bounds__(64) void segment_kernel(
    const float* __restrict__ bnd, int* __restrict__ nchunks,
    int* __restrict__ starts, int* __restrict__ lens) {
  const int b = blockIdx.x;
  const int lane = threadIdx.x;
  int running = 0;
  for (int g = 0; g < SEQ / 64; ++g) {
    int s = g * 64 + lane;
    bool isb = bnd[b * SEQ + s] > THRESH;
    unsigned long long mask = __ballot(isb ? 1 : 0);
    int excl = __popcll(mask & ((1ULL << lane) - 1ULL));
    if (isb) {
      int c = running + excl;
      if (c <= MAXC) starts[b * (MAXC + 1) + c] = s;
    }
    running += __popcll(mask);
  }
  if (lane == 0) nchunks[b] = running;
  __syncthreads();
  int ncl = min(running, MAXC);
  for (int c = lane; c < MAXC; c += 64) {
    int v = 0;
    if (c < ncl) {
      int st = starts[b * (MAXC + 1) + c];
      int en = (c + 1 < running) ? starts[b * (MAXC + 1) + c + 1] : SEQ;
      v = en - st;
    }
    lens[b * MAXC + c] = v;
  }
}

// --------------------------------------------- 128x256 pipelined QKV GEMM
// R12-proven pipeline (3 buffers, depth-2, counted vmcnt(3), single-type
// LDS-DMA staging, sigma swizzle). NEW: column-major bid decomposition so
// each XCD's active block window covers ONE 256-col B-strip (0.79MB ->
// L2-resident) instead of all 18 strips (14MB >> 4MB L2). A streams via L3.
__global__ __launch_bounds__(512, 4) void gemmQKV_kernel(
    const u16* __restrict__ A, const u16* __restrict__ B,
    const int M, const int N, const int K,
    const float* __restrict__ bias, u16* __restrict__ outB) {
  __shared__ __align__(16) u16 lds[3][12288];
  const int tid = threadIdx.x;
  const int wid = tid >> 6;
  const int lane = tid & 63;
  const int cpx = gridDim.x >> 3;
  const int bid = ((int)blockIdx.x & 7) * cpx + ((int)blockIdx.x >> 3);
  const int MX = M >> 7;                 // M / 128 row-tiles
  const int row0 = (bid % MX) << 7;      // col-major: row fastest
  const int col0 = (bid / MX) << 8;

  const int wr = wid >> 2;
  const int wc = wid & 3;
  const int rr = lane & 15;
  const int kg = lane >> 4;
  const int cw = rr * 4 + kg;
  const int slot = cw ^ ((cw >> 3) & 7);
  int srA, skA;
  { const int c = tid & 63; const int g = tid >> 6;
    const int gc = c ^ ((c >> 3) & 7);
    srA = g * 16 + (gc >> 2); skA = (gc & 3) * 8; }
  int srB[2], skB[2];
#pragma unroll
  for (int i = 0; i < 2; ++i) {
    const int s = i * 512 + tid;
    const int c = s & 63; const int g = s >> 6;
    const int gc = c ^ ((c >> 3) & 7);
    srB[i] = g * 16 + (gc >> 2); skB[i] = (gc & 3) * 8;
  }

  const int NT = K >> 5;

#define STAGE(t)                                                              \
  {                                                                           \
    const int _b = (t) % 3;                                                   \
    const int _kb = (t) << 5;                                                 \
    u16* ga = const_cast<u16*>(A) + (size_t)(row0 + srA) * K + _kb + skA;     \
    __builtin_amdgcn_global_load_lds(                                         \
        (__attribute__((address_space(1))) void*)ga,                          \
        (__attribute__((address_space(3))) void*)&lds[_b][(wid * 64) * 8],    \
        16, 0, 0);                                                            \
    _Pragma("unroll") for (int i = 0; i < 2; ++i) {                           \
      u16* gb = const_cast<u16*>(B) + (size_t)(col0 + srB[i]) * K + _kb +     \
                skB[i];                                                       \
      __builtin_amdgcn_global_load_lds(                                       \
          (__attribute__((address_space(1))) void*)gb,                        \
          (__attribute__((address_space(3))) void*)&lds[_b]                   \
              [4096 + (i * 512 + wid * 64) * 8], 16, 0, 0);                   \
    }                                                                         \
  }

  f32x4 acc[4][4] = {};

  STAGE(0); STAGE(1);
  asm volatile("s_waitcnt vmcnt(3)" ::: "memory");
  __builtin_amdgcn_s_barrier();

  for (int t = 0; t < NT; ++t) {
    const int buf = t % 3;
    bf16x8 bf[4], af[4];
#pragma unroll
    for (int n = 0; n < 4; ++n)
      bf[n] = *(const bf16x8*)&lds[buf][4096 + ((wc * 4 + n) * 64 + slot) * 8];
#pragma unroll
    for (int m = 0; m < 4; ++m)
      af[m] = *(const bf16x8*)&lds[buf][((wr * 4 + m) * 64 + slot) * 8];
    if (t + 2 < NT) STAGE(t + 2);
    __builtin_amdgcn_s_setprio(1);
#pragma unroll
    for (int m = 0; m < 4; ++m)
#pragma unroll
      for (int n = 0; n < 4; ++n)
        acc[m][n] = __builtin_amdgcn_mfma_f32_16x16x32_bf16(af[m], bf[n], acc[m][n], 0, 0, 0);
    __builtin_amdgcn_s_setprio(0);
    if (t + 2 < NT) {
      asm volatile("s_waitcnt vmcnt(3)" ::: "memory");
    } else if (t + 1 < NT) {
      asm volatile("s_waitcnt vmcnt(0)" ::: "memory");
    }
    __builtin_amdgcn_s_barrier();
  }
#undef STAGE

#pragma unroll
  for (int m = 0; m < 4; ++m) {
#pragma unroll
    for (int n = 0; n < 4; ++n) {
      const int col = col0 + wc * 64 + n * 16 + rr;
      const float bs = bias[col];
#pragma unroll
      for (int j = 0; j < 4; ++j) {
        const int row = row0 + wr * 64 + m * 16 + (lane >> 4) * 4 + j;
        outB[(size_t)row * N + col] = f2bf(acc[m][n][j] + bs);
      }
    }
  }
}

// ------------------------------------------------------------ 128x64 GEMM
// (R12-proven.) 3-buffer depth-2 counted-vmcnt template; 4 blocks/CU.
template <int MODE>
__global__ __launch_bounds__(256, 4) void gemm_bf16_kernel(
    const u16* __restrict__ A, const u16* __restrict__ B,
    const int M, const int N, const int K,
    const float* __restrict__ bias,
    u16* __restrict__ outB, float* __restrict__ outF,
    const int* __restrict__ lens, const float* __restrict__ semb,
    const float* __restrict__ pos) {
  __shared__ __align__(16) u16 As[3][128 * 32];
  __shared__ __align__(16) u16 Bs[3][64 * 32];
  const int tid = threadIdx.x;
  const int wave = tid >> 6;
  const int lane = tid & 63;
  const int row0 = blockIdx.y * 128;
  const int col0 = blockIdx.x * 64;
  const int wm = (wave >> 1) * 64;
  const int wn = (wave & 1) * 32;
  const int gch = lane ^ ((lane >> 3) & 7);
  const int sr = gch >> 2;
  const int sc = (gch & 3) * 8;
  const int rr = lane & 15;
  const int kg = lane >> 4;
  const int cwant = rr * 4 + kg;
  const int slot = cwant ^ ((cwant >> 3) & 7);
  const int NT = K >> 5;
  f32x4 acc[4][2] = {};

#define STAGE64(t)                                                            \
  {                                                                           \
    const int _b = (t) % 3;                                                   \
    const int _k = (t) << 5;                                                  \
    _Pragma("unroll") for (int tt = 0; tt < 2; ++tt) {                        \
      const int li = wave * 2 + tt;                                           \
      u16* ga = const_cast<u16*>(A) + (size_t)(row0 + li * 16 + sr) * K +     \
                _k + sc;                                                      \
      __builtin_amdgcn_global_load_lds(                                       \
          (__attribute__((address_space(1))) void*)ga,                        \
          (__attribute__((address_space(3))) void*)(As[_b] + li * 512), 16,   \
          0, 0);                                                              \
    }                                                                         \
    u16* gb = const_cast<u16*>(B) + (size_t)(col0 + wave * 16 + sr) * K +     \
              _k + sc;                                                        \
    __builtin_amdgcn_global_load_lds(                                         \
        (__attribute__((address_space(1))) void*)gb,                          \
        (__attribute__((address_space(3))) void*)(Bs[_b] + wave * 512), 16,   \
        0, 0);                                                                \
  }

  STAGE64(0); STAGE64(1);
  asm volatile("s_waitcnt vmcnt(3)" ::: "memory");
  __builtin_amdgcn_s_barrier();

  for (int t = 0; t < NT; ++t) {
    const int cb = t % 3;
    bf16x8 bfr[2], af[4];
#pragma unroll
    for (int n = 0; n < 2; ++n)
      bfr[n] = *(const bf16x8*)(Bs[cb] + ((wn >> 4) + n) * 512 + slot * 8);
#pragma unroll
    for (int m = 0; m < 4; ++m)
      af[m] = *(const bf16x8*)(As[cb] + ((wm >> 4) + m) * 512 + slot * 8);
    if (t + 2 < NT) STAGE64(t + 2);
#pragma unroll
    for (int m = 0; m < 4; ++m)
#pragma unroll
      for (int n = 0; n < 2; ++n)
        acc[m][n] = __builtin_amdgcn_mfma_f32_16x16x32_bf16(af[m], bfr[n], acc[m][n], 0, 0, 0);
    if (t + 2 < NT) {
      asm volatile("s_waitcnt vmcnt(3)" ::: "memory");
    } else if (t + 1 < NT) {
      asm volatile("s_waitcnt vmcnt(0)" ::: "memory");
    }
    __builtin_amdgcn_s_barrier();
  }
#undef STAGE64

  const int rg = (lane >> 4) * 4;
#pragma unroll
  for (int m = 0; m < 4; ++m) {
#pragma unroll
    for (int n = 0; n < 2; ++n) {
      const int col = col0 + wn + n * 16 + rr;
#pragma unroll
      for (int j = 0; j < 4; ++j) {
        const int row = row0 + wm + m * 16 + rg + j;
        float v = acc[m][n][j];
        if (MODE == 2) {
          const int len = lens[row];
          float val = 0.f;
          if (len > 0) {
            const int si = len < 1023 ? len : 1023;
            val = v + bias[col] + semb[(size_t)si * DM + col];
          }
          val += pos[(size_t)(row & (MAXC - 1)) * DM + col];
          outB[(size_t)row * N + col] = f2bf(val);
        } else if (MODE == 3) {
          float z = v + bias[col];
          float gel = 0.5f * z * (1.f + erff(z * 0.70710678118654752440f));
          outB[(size_t)row * N + col] = f2bf(gel);
        } else {
          outF[(size_t)row * N + col] = v + bias[col];
        }
      }
    }
  }
}

// ----------------------------------------------------- chunk attention v6
// One wave per (h,c,b). v5 + de-serialized V-pool: g broadcasts hoisted
// into an unrolled independent bpermute prefix (gv[]), V loads made
// unconditional clamped-address (invalid keys get g=0) so all loads
// pipeline instead of serializing with the FMA chain.
__global__ __launch_bounds__(64) void chunk_attn_kernel(
    const u16* __restrict__ qkv, const int* __restrict__ nchunks,
    const int* __restrict__ starts, const int* __restrict__ lens,
    u16* __restrict__ pooled) {
  __shared__ float g_lds[SEQ];
  const int h = blockIdx.x;
  const int c = blockIdx.y;
  const int b = blockIdx.z;
  const int lane = threadIdx.x;
  const int nc = min(nchunks[b], MAXC);
  u16* prow = pooled + ((size_t)(b * MAXC + c)) * DM + h * DHEAD;
  if (c >= nc) {  // empty chunk: pooled ctx = 0
    U2 z; z.x = 0; z.y = 0;
    *(U2*)(prow + lane * 2) = z;
    return;
  }
  const int s0 = starts[b * (MAXC + 1) + c];
  const int L = lens[b * MAXC + c];
  const u16* Qb = qkv + ((size_t)(b * SEQ + s0)) * QKVN + h * DHEAD;
  const u16* Kb = Qb + DM;
  const u16* Vb = Qb + 2 * DM;

  const int col = lane & 15;
  const int grp = lane >> 4;
  const float scale = 0.08838834764831845f;  // 1/sqrt(128)
  const int half = lane >> 5;       // key parity this lane pools
  const int dl4 = (lane & 31) * 4;  // dim base (4 dims/lane over 32 lanes)

  float a[4] = {0.f, 0.f, 0.f, 0.f};

  if (L <= 16) {
    // ---------------- register-only single-tile path
    const int rc = col < L ? col : (L - 1);
    bf16x8 qf[4], kf[4];
#pragma unroll
    for (int s = 0; s < 4; ++s) {
      qf[s] = *(const bf16x8*)(Qb + (size_t)rc * QKVN + s * 32 + grp * 8);
      kf[s] = *(const bf16x8*)(Kb + (size_t)rc * QKVN + s * 32 + grp * 8);
    }
    f32x4 sc = {0.f, 0.f, 0.f, 0.f};
#pragma unroll
    for (int s = 0; s < 4; ++s)
      sc = __builtin_amdgcn_mfma_f32_16x16x32_bf16(qf[s], kf[s], sc, 0, 0, 0);
    const bool kvalid = col < L;
    float g = 0.f;
#pragma unroll
    for (int j = 0; j < 4; ++j) {
      float sj = sc[j] * scale;
      float mv = kvalid ? sj : -3e38f;
      mv = fmaxf(mv, __shfl_xor(mv, 1));
      mv = fmaxf(mv, __shfl_xor(mv, 2));
      mv = fmaxf(mv, __shfl_xor(mv, 4));
      mv = fmaxf(mv, __shfl_xor(mv, 8));
      float pv = kvalid ? __expf(sj - mv) : 0.f;
      float dv = pv;
      dv += __shfl_xor(dv, 1);
      dv += __shfl_xor(dv, 2);
      dv += __shfl_xor(dv, 4);
      dv += __shfl_xor(dv, 8);
      const bool rv = (grp * 4 + j) < L;
      g += rv ? pv / dv : 0.f;
    }
    g += __shfl_xor(g, 16);
    g += __shfl_xor(g, 32);   // lanes 0-15 (replicated): column sums
    // hoisted broadcasts (8 independent bpermutes) + pipelined V loads
    float gv[8];
#pragma unroll
    for (int i = 0; i < 8; ++i) {
      const int jj = 2 * i + half;
      float gb = __shfl(g, jj < 16 ? jj : 0);
      gv[i] = (jj < L) ? gb : 0.f;
    }
#pragma unroll
    for (int i = 0; i < 8; ++i) {
      const int jj = 2 * i + half;
      const int jc = jj < L ? jj : (L - 1);   // clamped addr, g=0 if invalid
      if (2 * i < L) {
        U4 vv = *(const U4*)(Vb + (size_t)jc * QKVN + dl4);
        a[0] += gv[i] * bf2f(vv.x); a[1] += gv[i] * bf2f(vv.y);
        a[2] += gv[i] * bf2f(vv.z); a[3] += gv[i] * bf2f(vv.w);
      }
    }
  } else {
    // ---------------- general tiled path (wave-local LDS g, no barriers)
    float* gw = g_lds;
    for (int j = lane; j < L; j += 64) gw[j] = 0.f;
    const int NT = (L + 15) >> 4;
    for (int qt = 0; qt < NT; ++qt) {
      const int qr = qt * 16 + col;
      const int qrc = qr < L ? qr : (L - 1);
      bf16x8 qf[4];
#pragma unroll
      for (int s = 0; s < 4; ++s)
        qf[s] = *(const bf16x8*)(Qb + (size_t)qrc * QKVN + s * 32 + grp * 8);

      float m[4] = {-3e38f, -3e38f, -3e38f, -3e38f};
      float den[4] = {0.f, 0.f, 0.f, 0.f};
      for (int kt = 0; kt < NT; ++kt) {
        const int kr = kt * 16 + col;
        const bool kvalid = kr < L;
        const int krc = kvalid ? kr : (L - 1);
        f32x4 sc = {0.f, 0.f, 0.f, 0.f};
#pragma unroll
        for (int s = 0; s < 4; ++s) {
          bf16x8 kf = *(const bf16x8*)(Kb + (size_t)krc * QKVN + s * 32 + grp * 8);
          sc = __builtin_amdgcn_mfma_f32_16x16x32_bf16(qf[s], kf, sc, 0, 0, 0);
        }
#pragma unroll
        for (int j = 0; j < 4; ++j) {
          float sj = sc[j] * scale;
          float mv = kvalid ? sj : -3e38f;
          mv = fmaxf(mv, __shfl_xor(mv, 1));
          mv = fmaxf(mv, __shfl_xor(mv, 2));
          mv = fmaxf(mv, __shfl_xor(mv, 4));
          mv = fmaxf(mv, __shfl_xor(mv, 8));
          float mn = fmaxf(m[j], mv);
          float pv = kvalid ? __expf(sj - mn) : 0.f;
          pv += __shfl_xor(pv, 1);
          pv += __shfl_xor(pv, 2);
          pv += __shfl_xor(pv, 4);
          pv += __shfl_xor(pv, 8);
          den[j] = den[j] * __expf(m[j] - mn) + pv;
          m[j] = mn;
        }
      }
      float inv[4];
#pragma unroll
      for (int j = 0; j < 4; ++j) {
        const bool rv = (qt * 16 + grp * 4 + j) < L;
        inv[j] = rv ? 1.f / den[j] : 0.f;
      }
      for (int kt = 0; kt < NT; ++kt) {
        const int kr = kt * 16 + col;
        const bool kvalid = kr < L;
        const int krc = kvalid ? kr : (L - 1);
        f32x4 sc = {0.f, 0.f, 0.f, 0.f};
#pragma unroll
        for (int s = 0; s < 4; ++s) {
          bf16x8 kf = *(const bf16x8*)(Kb + (size_t)krc * QKVN + s * 32 + grp * 8);
          sc = __builtin_amdgcn_mfma_f32_16x16x32_bf16(qf[s], kf, sc, 0, 0, 0);
        }
        float colsum = 0.f;
#pragma unroll
        for (int j = 0; j < 4; ++j)
          colsum += __expf(sc[j] * scale - m[j]) * inv[j];
        colsum += __shfl_xor(colsum, 16);
        colsum += __shfl_xor(colsum, 32);
        if (grp == 0 && kvalid) gw[kt * 16 + col] += colsum;
      }
    }
    for (int j = 0; j < L; j += 2) {
      const int jj = j + half;
      const bool jv = jj < L;
      float gj = jv ? gw[jj] : 0.f;
      const int jc = jv ? jj : 0;
      U4 vv = *(const U4*)(Vb + (size_t)jc * QKVN + dl4);
      a[0] += gj * bf2f(vv.x); a[1] += gj * bf2f(vv.y);
      a[2] += gj * bf2f(vv.z); a[3] += gj * bf2f(vv.w);
    }
  }
  const float invL = 1.f / (float)L;
#pragma unroll
  for (int i = 0; i < 4; ++i) {
    a[i] += __shfl_xor(a[i], 32);
    a[i] *= invL;
  }
  if (lane < 32) {
    U4 r; r.x = f2bf(a[0]); r.y = f2bf(a[1]); r.z = f2bf(a[2]); r.w = f2bf(a[3]);
    *(U4*)(prow + dl4) = r;
  }
}

// ---------------------------------------------------------------- LayerNorm
__global__ __launch_bounds__(256) void ln_kernel(
    const float* __restrict__ h2, const float* __restrict__ gamma,
    const float* __restrict__ beta, float* __restrict__ out) {
  const int row = blockIdx.x;
  const float* x = h2 + (size_t)row * DM;
  float* o = out + (size_t)row * DM;
  const int tid = threadIdx.x;
  float v[6];
  float s = 0.f;
#pragma unroll
  for (int i = 0; i < 6; ++i) { v[i] = x[tid + i * 256]; s += v[i]; }
  __shared__ float red[8];
#pragma unroll
  for (int off = 32; off; off >>= 1) s += __shfl_xor(s, off);
  if ((tid & 63) == 0) red[tid >> 6] = s;
  __syncthreads();
  const float mu = (red[0] + red[1] + red[2] + red[3]) * (1.f / (float)DM);
  float vs = 0.f;
#pragma unroll
  for (int i = 0; i < 6; ++i) { float d = v[i] - mu; vs += d * d; }
#pragma unroll
  for (int off = 32; off; off >>= 1) vs += __shfl_xor(vs, off);
  __shared__ float red2[8];
  if ((tid & 63) == 0) red2[tid >> 6] = vs;
  __syncthreads();
  const float var = (red2[0] + red2[1] + red2[2] + red2[3]) * (1.f / (float)DM);
  const float inv = rsqrtf(var + 1e-5f);
#pragma unroll
  for (int i = 0; i < 6; ++i) {
    const int cidx = tid + i * 256;
    o[cidx] = (v[i] - mu) * inv * gamma[cidx] + beta[cidx];
  }
}

// ------------------------------------------------------------------ launch
extern "C" void kernel_launch(void* const* d_in, const int* in_sizes, int n_in,
                              void* d_out, int out_size, void* d_ws, size_t ws_size,
                              hipStream_t stream) {
  const float* x    = (const float*)d_in[0];
  const float* bnd  = (const float*)d_in[1];
  const float* wqkv = (const float*)d_in[2];
  const float* bqkv = (const float*)d_in[3];
  const float* wout = (const float*)d_in[4];
  const float* bout = (const float*)d_in[5];
  const float* w1   = (const float*)d_in[6];
  const float* b1   = (const float*)d_in[7];
  const float* w2   = (const float*)d_in[8];
  const float* b2   = (const float*)d_in[9];
  const float* lng  = (const float*)d_in[10];
  const float* lnb  = (const float*)d_in[11];
  const float* pos  = (const float*)d_in[12];
  const float* semb = (const float*)d_in[13];
  float* out = (float*)d_out;

  char* ws = (char*)d_ws;
  size_t off = 0;
  auto alloc = [&](size_t bytes) -> char* {
    char* p = ws + off;
    off += (bytes + 255) & ~(size_t)255;
    return p;
  };
  u16* x_bf    = (u16*)alloc((size_t)NB * SEQ * DM * 2);
  u16* wqkv_bf = (u16*)alloc((size_t)3 * DM * DM * 2);
  u16* wout_bf = (u16*)alloc((size_t)DM * DM * 2);
  u16* w1_bf   = (u16*)alloc((size_t)2 * DM * DM * 2);
  u16* w2_bf   = (u16*)alloc((size_t)2 * DM * DM * 2);
  u16* qkv_bf  = (u16*)alloc((size_t)NB * SEQ * QKVN * 2);
  int* nchunks = (int*)alloc(NB * 4);
  int* starts  = (int*)alloc(NB * (MAXC + 1) * 4);
  int* lens    = (int*)alloc(NB * MAXC * 4);
  u16* pooled  = (u16*)alloc((size_t)NB * MAXC * DM * 2);
  u16* chunks  = (u16*)alloc((size_t)NB * MAXC * DM * 2);
  u16* h1      = (u16*)alloc((size_t)NB * MAXC * 2 * DM * 2);
  float* h2    = (float*)alloc((size_t)NB * MAXC * DM * 4);
  (void)ws_size; (void)in_sizes; (void)n_in; (void)out_size;

  cvt5_bf16_kernel<<<2048, 256, 0, stream>>>(
      x, x_bf, NB * SEQ * DM / 4,
      wqkv, wqkv_bf, 3 * DM * DM / 4,
      wout, wout_bf, DM * DM / 4,
      w1, w1_bf, 2 * DM * DM / 4,
      w2, w2_bf, 2 * DM * DM / 4);

  segment_kernel<<<NB, 64, 0, stream>>>(bnd, nchunks, starts, lens);

  // QKV projection: [8192,1536] @ [4608,1536]^T, 128x256 tiles, 2 blocks/CU
  gemmQKV_kernel<<<(NB * SEQ / 128) * (QKVN / 256), 512, 0, stream>>>(
      x_bf, wqkv_bf, NB * SEQ, QKVN, DM, bqkv, qkv_bf);

  chunk_attn_kernel<<<dim3(NHEAD, MAXC, NB), 64, 0, stream>>>(
      qkv_bf, nchunks, starts, lens, pooled);

  gemm_bf16_kernel<2><<<dim3(DM / 64, NB * MAXC / 128), 256, 0, stream>>>(
      pooled, wout_bf, NB * MAXC, DM, DM, bout, chunks, nullptr, lens, semb, pos);

  gemm_bf16_kernel<3><<<dim3(2 * DM / 64, NB * MAXC / 128), 256, 0, stream>>>(
      chunks, w1_bf, NB * MAXC, 2 * DM, DM, b1, h1, nullptr, nullptr, nullptr, nullptr);

  gemm_bf16_kernel<4><<<dim3(DM / 64, NB * MAXC / 128), 256, 0, stream>>>(
      h1, w2_bf, NB * MAXC, DM, 2 * DM, b2, nullptr, h2, nullptr, nullptr, nullptr);

  ln_kernel<<<NB * MAXC, 256, 0, stream>>>(h2, lng, lnb, out);
}